// Round 12
// baseline (3933.375 us; speedup 1.0000x reference)
//
#include <hip/hip_runtime.h>
#include <stdint.h>

// GP posterior via batched CG. Khat bf16 (128 MB). Matvec = 256x256x64 8-phase
// counted-vmcnt MFMA GEMM (87% dense peak). CG dots fused into the 256² gemm
// epilogue (scattered reads proven free on this structure, r10/r11 FINAL mode).
// cg_upd = pure streaming update with inline scalar recurrence (no reductions).
// State (scal, pq8) double-buffered by iteration parity.

#define N_TRAIN 8192
#define N_TEST  4096
#define DIM     16
#define KDIM    8192
#define CG_ITERS 5
#define NT      (KDIM / 64)   // 128 K-tiles of BK=64

using f32x4  = __attribute__((ext_vector_type(4))) float;
using bf16x8 = __attribute__((ext_vector_type(8))) short;

static __device__ __forceinline__ unsigned short f2bf(float f) {
  unsigned u = __float_as_uint(f);
  u = (u + 0x7FFFu + ((u >> 16) & 1u)) >> 16;   // RNE
  return (unsigned short)u;
}
static __device__ __forceinline__ float bf2f(unsigned short h) {
  return __uint_as_float(((unsigned)h) << 16);
}
static __device__ __forceinline__ float rnd_bf(float f) { return bf2f(f2bf(f)); }

__device__ __forceinline__ void gl_lds16(const void* g, void* l) {
  __builtin_amdgcn_global_load_lds(
      (const __attribute__((address_space(1))) unsigned int*)g,
      (__attribute__((address_space(3))) unsigned int*)l, 16, 0, 0);
}

// ---- prep: rows scaled by 1/lengthscale + squared norms ----
__global__ void prep_kernel(const float* __restrict__ tx, const float* __restrict__ xx,
                            const float* __restrict__ ls,
                            float* __restrict__ As, float* __restrict__ an,
                            float* __restrict__ Bs, float* __restrict__ bn) {
  int i = blockIdx.x * 256 + threadIdx.x;
  if (i < N_TRAIN) {
    float s = 0.f;
    #pragma unroll
    for (int d = 0; d < DIM; ++d) {
      float v = tx[(size_t)i * DIM + d] / ls[d];
      As[(size_t)i * DIM + d] = v; s += v * v;
    }
    an[i] = s;
  } else if (i < N_TRAIN + N_TEST) {
    int j = i - N_TRAIN;
    float s = 0.f;
    #pragma unroll
    for (int d = 0; d < DIM; ++d) {
      float v = xx[(size_t)j * DIM + d] / ls[d];
      Bs[(size_t)j * DIM + d] = v; s += v * v;
    }
    bn[j] = s;
  }
}

// ---- kernel-matrix builder: thread owns ADJACENT cols (4B coalesced stores) ----
template <bool NOISE>
__global__ __launch_bounds__(256) void build_kernel(
    const float* __restrict__ RI, const float* __restrict__ nI,
    const float* __restrict__ RJ, const float* __restrict__ nJ,
    unsigned short* __restrict__ O1,
    const float* __restrict__ osc, const float* __restrict__ noi)
{
  __shared__ float aI[128 * DIM];
  __shared__ float sI[128];
  int t = threadIdx.x;
  int j0 = blockIdx.x * 512, i0 = blockIdx.y * 128;
  for (int e = t; e < 128 * DIM; e += 256) aI[e] = RI[(size_t)i0 * DIM + e];
  if (t < 128) sI[t] = nI[i0 + t];
  __syncthreads();

  int ja = j0 + 2 * t, jb = ja + 1;
  f32x4 aj0[4], aj1[4];
  const f32x4* RJa = (const f32x4*)(RJ + (size_t)ja * DIM);
  const f32x4* RJb = (const f32x4*)(RJ + (size_t)jb * DIM);
  #pragma unroll
  for (int q = 0; q < 4; ++q) { aj0[q] = RJa[q]; aj1[q] = RJb[q]; }
  float nja = nJ[ja], njb = nJ[jb];
  float s = osc[0], sn = noi[0];

  for (int ic = 0; ic < 128; ic += 2) {
    f32x4 rv[2][4];
    #pragma unroll
    for (int r = 0; r < 2; ++r)
      #pragma unroll
      for (int q = 0; q < 4; ++q)
        rv[r][q] = *(const f32x4*)&aI[(ic + r) * DIM + q * 4];
    #pragma unroll
    for (int r = 0; r < 2; ++r) {
      int i = ic + r;
      float d0 = 0.f, d1 = 0.f;
      #pragma unroll
      for (int q = 0; q < 4; ++q) {
        f32x4 ai = rv[r][q];
        d0 += ai[0]*aj0[q][0] + ai[1]*aj0[q][1] + ai[2]*aj0[q][2] + ai[3]*aj0[q][3];
        d1 += ai[0]*aj1[q][0] + ai[1]*aj1[q][1] + ai[2]*aj1[q][2] + ai[3]*aj1[q][3];
      }
      float d2a = fmaxf(sI[i] + nja - 2.f * d0, 0.f);
      float d2b = fmaxf(sI[i] + njb - 2.f * d1, 0.f);
      float va = s * __expf(-0.5f * d2a);
      float vb = s * __expf(-0.5f * d2b);
      if (NOISE && (i0 + i == ja)) va += sn;
      if (NOISE && (i0 + i == jb)) vb += sn;
      unsigned pack = (unsigned)f2bf(va) | ((unsigned)f2bf(vb) << 16);
      *(unsigned*)&O1[(size_t)(i0 + i) * KDIM + ja] = pack;
    }
  }
}

// ============  256x256 8-phase pipelined MFMA GEMM (counted vmcnt)  ============
// MODE 0 (FIRST, p==r==b): store Q; dots {pq,qq,yq,pp,yp} -> slots {0,2,3,4,5}
// MODE 1 (MID):            store Q; dots {pq,rq,qq,yq}    -> slots {0,1,2,3}
// MODE 2 (LAST):           no Q store; dot {pq}           -> slot 0

__device__ __forceinline__ void stage_h(const char* gtile, int kbyte,
                                        char* ldsdst, int tid, int wave) {
  #pragma unroll
  for (int q = 0; q < 2; ++q) {
    int o = q * 8192 + tid * 16;
    int r = o >> 7;
    int c = (o & 127) ^ ((r & 7) << 4);
    gl_lds16(gtile + (size_t)r * (KDIM * 2) + kbyte + c,
             ldsdst + q * 8192 + wave * 1024);   // wave-uniform dest, HW adds lane*16
  }
}

template <int MODE>
__global__ __launch_bounds__(512, 1) void gemm256(
    const unsigned short* __restrict__ A,   // p (Rb for it0, else Pb) [M][KDIM]
    const unsigned short* __restrict__ Bm,  // Khat [8192][KDIM] bf16
    unsigned short* __restrict__ Cq,        // Q [M][8192] bf16
    int gy,
    const unsigned short* __restrict__ Rm,  // residual (MODE 1)
    const float* __restrict__ y,            // train_y [8192] f32
    float* __restrict__ pq8)                // [C][8] dot slots (atomic), parity buf
{
  __shared__ char Ab[2][2][16384];   // [buf][half][128x64 bf16] = 64 KB
  __shared__ char Bb[2][2][16384];   // 64 KB
  const int tid = threadIdx.x, lane = tid & 63, wave = tid >> 6;
  const int wm = wave >> 2, wn = wave & 3;          // 2M x 4N
  const int nwg = gridDim.x, orig = blockIdx.x;
  const int wgid = (orig & 7) * (nwg >> 3) + (orig >> 3);   // XCD-chunked
  const int bx = wgid / gy, by = wgid % gy;
  const size_t HALF = (size_t)128 * KDIM * 2;

  const char* bA = (const char*)(A  + (size_t)(by * 256) * KDIM);
  const char* bB = (const char*)(Bm + (size_t)(bx * 256) * KDIM);

  const int ar = wm * 64 + (lane & 15);
  const int br = wn * 32 + (lane & 15);
  const int hi = (lane >> 4) * 16;
  int aoff[4][2], boff[2][2];
  #pragma unroll
  for (int mf = 0; mf < 4; ++mf)
    #pragma unroll
    for (int kk = 0; kk < 2; ++kk)
      aoff[mf][kk] = (ar + mf * 16) * 128 + ((hi + kk * 64) ^ ((ar & 7) << 4));
  #pragma unroll
  for (int nf = 0; nf < 2; ++nf)
    #pragma unroll
    for (int kk = 0; kk < 2; ++kk)
      boff[nf][kk] = (br + nf * 16) * 128 + ((hi + kk * 64) ^ ((br & 7) << 4));

  f32x4 acc[2][2][4][2] = {};   // [mh][nh][mf][nf]
  bf16x8 aR[4][2], bR[2][2][2];

#define BAR() __builtin_amdgcn_s_barrier()
#define PRIO1 __builtin_amdgcn_s_setprio(1)
#define PRIO0 __builtin_amdgcn_s_setprio(0)
#define FENCE8() asm volatile("s_waitcnt vmcnt(8)" ::: "memory")
#define FENCE6() asm volatile("s_waitcnt vmcnt(6)" ::: "memory")
#define FENCE0() asm volatile("s_waitcnt vmcnt(0)" ::: "memory")
#define STAGE_A(buf, mh, kb) stage_h(bA + ((mh) ? HALF : 0), kb, &Ab[buf][mh][0], tid, wave)
#define STAGE_B(buf, mh, kb) stage_h(bB + ((mh) ? HALF : 0), kb, &Bb[buf][mh][0], tid, wave)
#define LOAD_A(buf, mh)                                                        \
  { _Pragma("unroll") for (int mf = 0; mf < 4; ++mf)                           \
      _Pragma("unroll") for (int kk = 0; kk < 2; ++kk)                         \
        aR[mf][kk] = *(const bf16x8*)(&Ab[buf][mh][0] + aoff[mf][kk]); }
#define LOAD_B(buf, nh)                                                        \
  { _Pragma("unroll") for (int nf = 0; nf < 2; ++nf)                           \
      _Pragma("unroll") for (int kk = 0; kk < 2; ++kk)                         \
        bR[nh][nf][kk] = *(const bf16x8*)(&Bb[buf][nh][0] + boff[nf][kk]); }
#define MFMA16(mh, nh)                                                         \
  { _Pragma("unroll") for (int kk = 0; kk < 2; ++kk)                           \
      _Pragma("unroll") for (int mf = 0; mf < 4; ++mf)                         \
        _Pragma("unroll") for (int nf = 0; nf < 2; ++nf)                       \
          acc[mh][nh][mf][nf] = __builtin_amdgcn_mfma_f32_16x16x32_bf16(       \
              aR[mf][kk], bR[nh][nf][kk], acc[mh][nh][mf][nf], 0, 0, 0); }

  STAGE_A(0, 0, 0);   STAGE_B(0, 0, 0);   STAGE_B(0, 1, 0);   STAGE_A(0, 1, 0);
  STAGE_A(1, 0, 128); STAGE_B(1, 0, 128); STAGE_B(1, 1, 128); STAGE_A(1, 1, 128);
  FENCE6();
  BAR();

  for (int t = 0; t < NT; t += 2) {
    const bool g = (t + 2 < NT);
    const int kb2 = (t + 2) * 128, kb3 = (t + 3) * 128;
    LOAD_A(0, 0); LOAD_B(0, 0);
    BAR(); PRIO1; MFMA16(0, 0); PRIO0; BAR();
    if (g) STAGE_A(0, 0, kb2);
    LOAD_B(0, 1);
    BAR(); PRIO1; MFMA16(0, 1); PRIO0; BAR();
    if (g) STAGE_B(0, 0, kb2);
    LOAD_A(0, 1);
    BAR(); PRIO1; MFMA16(1, 0); PRIO0; BAR();
    if (g) { STAGE_B(0, 1, kb2); STAGE_A(0, 1, kb2); }
    BAR(); PRIO1; MFMA16(1, 1); PRIO0;
    if (g) { FENCE8(); } else { FENCE0(); }
    BAR();
    LOAD_A(1, 0); LOAD_B(1, 0);
    BAR(); PRIO1; MFMA16(0, 0); PRIO0; BAR();
    if (g) STAGE_A(1, 0, kb3);
    LOAD_B(1, 1);
    BAR(); PRIO1; MFMA16(0, 1); PRIO0; BAR();
    if (g) STAGE_B(1, 0, kb3);
    LOAD_A(1, 1);
    BAR(); PRIO1; MFMA16(1, 0); PRIO0; BAR();
    if (g) { STAGE_B(1, 1, kb3); STAGE_A(1, 1, kb3); }
    BAR(); PRIO1; MFMA16(1, 1); PRIO0;
    if (g) { FENCE6(); }
    BAR();
  }

  const int bm = by * 256, bn = bx * 256;
  // Q store (verified C/D mapping: col = lane&15, row = (lane>>4)*4 + reg)
  if (MODE != 2) {
    #pragma unroll
    for (int mh = 0; mh < 2; ++mh)
      #pragma unroll
      for (int nh = 0; nh < 2; ++nh)
        #pragma unroll
        for (int mf = 0; mf < 4; ++mf)
          #pragma unroll
          for (int nf = 0; nf < 2; ++nf) {
            int row = bm + mh * 128 + wm * 64 + mf * 16 + (lane >> 4) * 4;
            int col = bn + nh * 128 + wn * 32 + nf * 16 + (lane & 15);
            #pragma unroll
            for (int rg = 0; rg < 4; ++rg)
              Cq[(size_t)(row + rg) * KDIM + col] = f2bf(acc[mh][nh][mf][nf][rg]);
          }
  }
  // fused dot epilogue (scattered reads: free on this structure per r10/r11)
  #pragma unroll
  for (int mh = 0; mh < 2; ++mh)
    #pragma unroll
    for (int mf = 0; mf < 4; ++mf)
      #pragma unroll
      for (int rg = 0; rg < 4; ++rg) {
        int row = bm + mh * 128 + wm * 64 + mf * 16 + (lane >> 4) * 4 + rg;
        float s0 = 0.f, s1 = 0.f, s2 = 0.f, s3 = 0.f, s4 = 0.f, s5 = 0.f;
        #pragma unroll
        for (int nh = 0; nh < 2; ++nh)
          #pragma unroll
          for (int nf = 0; nf < 2; ++nf) {
            int col = bn + nh * 128 + wn * 32 + nf * 16 + (lane & 15);
            float qv = (MODE == 2) ? acc[mh][nh][mf][nf][rg]
                                   : rnd_bf(acc[mh][nh][mf][nf][rg]);
            float pv = bf2f(A[(size_t)row * KDIM + col]);
            s0 += pv * qv;
            if (MODE == 0) {
              float yv = y[col];
              s2 += qv * qv; s3 += yv * qv; s4 += pv * pv; s5 += yv * pv;
            } else if (MODE == 1) {
              float yv = y[col];
              float rv = bf2f(Rm[(size_t)row * KDIM + col]);
              s1 += rv * qv; s2 += qv * qv; s3 += yv * qv;
            }
          }
        #pragma unroll
        for (int off = 1; off < 16; off <<= 1) {
          s0 += __shfl_xor(s0, off);
          if (MODE == 0) { s2 += __shfl_xor(s2, off); s3 += __shfl_xor(s3, off);
                           s4 += __shfl_xor(s4, off); s5 += __shfl_xor(s5, off); }
          if (MODE == 1) { s1 += __shfl_xor(s1, off); s2 += __shfl_xor(s2, off);
                           s3 += __shfl_xor(s3, off); }
        }
        if ((lane & 15) == 0) {
          float* d = &pq8[(size_t)row * 8];
          atomicAdd(&d[0], s0);
          if (MODE == 0) { atomicAdd(&d[2], s2); atomicAdd(&d[3], s3);
                           atomicAdd(&d[4], s4); atomicAdd(&d[5], s5); }
          if (MODE == 1) { atomicAdd(&d[1], s1); atomicAdd(&d[2], s2);
                           atomicAdd(&d[3], s3); }
        }
      }
#undef MFMA16
#undef LOAD_B
#undef LOAD_A
#undef STAGE_B
#undef STAGE_A
#undef FENCE0
#undef FENCE6
#undef FENCE8
#undef PRIO0
#undef PRIO1
#undef BAR
}

// ---- streaming update: inline scalar recurrence, no reductions/barriers.
// Block handles 2 columns. Zeroes its consumed pq8 slots at the end. ----
template <bool FIRST>
__global__ __launch_bounds__(256) void cg_upd(
    const unsigned short* __restrict__ Q, unsigned short* __restrict__ R,
    unsigned short* __restrict__ P,
    float* __restrict__ pq8,             // consumed dot buffer (this parity)
    const float* __restrict__ scal_old,  // state in  (ignored on FIRST)
    float* __restrict__ scal_new)        // state out
{
  int t = threadIdx.x;
  #pragma unroll
  for (int cc = 0; cc < 2; ++cc) {
    int c = blockIdx.x * 2 + cc;
    const float* d = &pq8[(size_t)c * 8];
    float s_pq = d[0];
    float rq, qq = d[2], yq = d[3];
    float rr, yp, yr, mean, bx;
    if (FIRST) {
      rq = d[0]; rr = d[4]; yp = d[5]; yr = d[5]; mean = 0.f; bx = 0.f;
    } else {
      rq = d[1];
      rr = scal_old[c*8+0]; yp = scal_old[c*8+1]; yr = scal_old[c*8+2];
      mean = scal_old[c*8+3]; bx = scal_old[c*8+4];
    }
    float alpha = rr / fmaxf(s_pq, 1e-30f);
    mean += alpha * yp;
    bx   += alpha * rr;
    float rrn = fmaxf(rr - 2.f * alpha * rq + alpha * alpha * qq, 0.f);
    float yrn = yr - alpha * yq;
    float beta = rrn / fmaxf(rr, 1e-30f);
    float ypn  = yrn + beta * yp;

    size_t base = (size_t)c * KDIM;
    #pragma unroll
    for (int k = 0; k < 4; ++k) {
      size_t off = base + k * 2048 + t * 8;
      bf16x8 q8 = *(const bf16x8*)&Q[off];
      bf16x8 r8 = *(const bf16x8*)&R[off];
      bf16x8 p8 = FIRST ? r8 : *(const bf16x8*)&P[off];
      bf16x8 wr, wp;
      #pragma unroll
      for (int e = 0; e < 8; ++e) {
        float rn = bf2f((unsigned short)r8[e]) -
                   alpha * bf2f((unsigned short)q8[e]);
        unsigned short hb = f2bf(rn);
        wr[e] = (short)hb;
        wp[e] = (short)f2bf(bf2f(hb) + beta * bf2f((unsigned short)p8[e]));
      }
      *(bf16x8*)&R[off] = wr;
      *(bf16x8*)&P[off] = wp;
    }
    if (t == 0) {
      scal_new[c*8+0] = rrn; scal_new[c*8+1] = ypn; scal_new[c*8+2] = yrn;
      scal_new[c*8+3] = mean; scal_new[c*8+4] = bx;
    }
    __syncthreads();                    // all reads of d done before zeroing
    if (t < 6) pq8[(size_t)c * 8 + t] = 0.f;   // ready for gemm(it+2)
  }
}

// ---- final outputs; zeroes consumed pq8 slots ----
__global__ void final_out(float* __restrict__ pq8, const float* __restrict__ scal,
                          const float* __restrict__ osc, const float* __restrict__ noi,
                          float* __restrict__ out, int c0, int C)
{
  int c = blockIdx.x * 256 + threadIdx.x;
  if (c >= C) return;
  float* d = &pq8[(size_t)c * 8];
  float rr = scal[c*8+0], yp = scal[c*8+1];
  float mean = scal[c*8+3], bx = scal[c*8+4];
  float alpha = rr / fmaxf(d[0], 1e-30f);
  mean += alpha * yp;
  bx   += alpha * rr;
  out[c0 + c] = mean;
  out[N_TEST + c0 + c] = osc[0] + noi[0] - bx;
  #pragma unroll
  for (int k = 0; k < 6; ++k) d[k] = 0.f;
}

extern "C" void kernel_launch(void* const* d_in, const int* in_sizes, int n_in,
                              void* d_out, int out_size, void* d_ws, size_t ws_size,
                              hipStream_t stream) {
  const float* tx = (const float*)d_in[0];
  const float* ty = (const float*)d_in[1];
  const float* xx = (const float*)d_in[2];
  const float* os = (const float*)d_in[3];
  const float* ls = (const float*)d_in[4];
  const float* ns = (const float*)d_in[5];
  float* out = (float*)d_out;
  (void)in_sizes; (void)n_in; (void)out_size;

  auto pad = [](size_t x) { return (x + 255) & ~(size_t)255; };
  size_t fixed = pad((size_t)N_TRAIN * KDIM * 2)
               + pad((size_t)N_TRAIN * DIM * 4) + pad((size_t)N_TRAIN * 4)
               + pad((size_t)N_TEST * DIM * 4) + pad((size_t)N_TEST * 4);
  int C = 4096;
  while (C > 256) {
    size_t tot = fixed + 3 * pad((size_t)C * KDIM * 2)
               + pad((size_t)C * 64) + pad((size_t)C * 64);
    if (tot <= ws_size) break;
    C >>= 1;
  }

  char* w = (char*)d_ws;
  auto alloc = [&](size_t bytes) { char* p = w; w += ((bytes + 255) & ~(size_t)255); return p; };
  unsigned short* Kb = (unsigned short*)alloc((size_t)N_TRAIN * KDIM * 2);
  float* As = (float*)alloc((size_t)N_TRAIN * DIM * 4);
  float* an = (float*)alloc((size_t)N_TRAIN * 4);
  float* Bs = (float*)alloc((size_t)N_TEST * DIM * 4);
  float* bn = (float*)alloc((size_t)N_TEST * 4);
  unsigned short* Rb = (unsigned short*)alloc((size_t)C * KDIM * 2);
  unsigned short* Pb = (unsigned short*)alloc((size_t)C * KDIM * 2);
  unsigned short* Qb = (unsigned short*)alloc((size_t)C * KDIM * 2);
  float* scal = (float*)alloc((size_t)C * 64);   // [2][C][8]
  float* pq8  = (float*)alloc((size_t)C * 64);   // [2][C][8]

  hipMemsetAsync(pq8, 0, (size_t)C * 64, stream);

  prep_kernel<<<48, 256, 0, stream>>>(tx, xx, ls, As, an, Bs, bn);

  build_kernel<true><<<dim3(KDIM / 512, N_TRAIN / 128), 256, 0, stream>>>(
      As, an, As, an, Kb, os, ns);

  for (int c0 = 0; c0 < N_TEST; c0 += C) {
    build_kernel<false><<<dim3(KDIM / 512, C / 128), 256, 0, stream>>>(
        Bs + (size_t)c0 * DIM, bn + c0, As, an, Rb, os, ns);
    int gy = C / 256;
    dim3 gg(32 * gy);
    float* scal0 = scal;                   // parity buffers
    float* scal1 = scal + (size_t)C * 8;
    for (int it = 0; it < CG_ITERS; ++it) {
      float* pqb = pq8 + (size_t)(it & 1) * C * 8;
      if (it == 0) {
        gemm256<0><<<gg, 512, 0, stream>>>(Rb, Kb, Qb, gy, Rb, ty, pqb);
        cg_upd<true><<<C / 2, 256, 0, stream>>>(Qb, Rb, Pb, pqb, nullptr, scal0);
      } else if (it < CG_ITERS - 1) {
        float* so = (it & 1) ? scal0 : scal1;   // state in
        float* sn_ = (it & 1) ? scal1 : scal0;  // state out
        gemm256<1><<<gg, 512, 0, stream>>>(Pb, Kb, Qb, gy, Rb, ty, pqb);
        cg_upd<false><<<C / 2, 256, 0, stream>>>(Qb, Rb, Pb, pqb, so, sn_);
      } else {
        // it == 4: state after it=3 lives in scal1
        gemm256<2><<<gg, 512, 0, stream>>>(Pb, Kb, Qb, gy, Rb, ty, pqb);
        final_out<<<(C + 255) / 256, 256, 0, stream>>>(pqb, scal1, os, ns, out, c0, C);
      }
    }
  }
}

// Round 13
// 2457.852 us; speedup vs baseline: 1.6003x; 1.6003x over previous
//
#include <hip/hip_runtime.h>
#include <stdint.h>

// GP posterior via batched CG. Khat bf16 (128 MB). Matvec = 256x256x64 8-phase
// counted-vmcnt MFMA GEMM (87% dense peak, r10-verified - DO NOT TOUCH).
// cg_step: r11 single-reduction recurrence form. Build: software-pipelined
// LDS reads (next-chunk prefetch) - the only change vs r11.

#define N_TRAIN 8192
#define N_TEST  4096
#define DIM     16
#define KDIM    8192
#define CG_ITERS 5
#define NT      (KDIM / 64)   // 128 K-tiles of BK=64

using f32x4  = __attribute__((ext_vector_type(4))) float;
using bf16x8 = __attribute__((ext_vector_type(8))) short;

static __device__ __forceinline__ unsigned short f2bf(float f) {
  unsigned u = __float_as_uint(f);
  u = (u + 0x7FFFu + ((u >> 16) & 1u)) >> 16;   // RNE
  return (unsigned short)u;
}
static __device__ __forceinline__ float bf2f(unsigned short h) {
  return __uint_as_float(((unsigned)h) << 16);
}

__device__ __forceinline__ void gl_lds16(const void* g, void* l) {
  __builtin_amdgcn_global_load_lds(
      (const __attribute__((address_space(1))) unsigned int*)g,
      (__attribute__((address_space(3))) unsigned int*)l, 16, 0, 0);
}

template <int N>
__device__ __forceinline__ void block_reduceN(float* v, float* sbuf) {
  #pragma unroll
  for (int off = 32; off > 0; off >>= 1)
    #pragma unroll
    for (int i = 0; i < N; ++i) v[i] += __shfl_down(v[i], off);
  int lane = threadIdx.x & 63, w = threadIdx.x >> 6;
  if (lane == 0)
    #pragma unroll
    for (int i = 0; i < N; ++i) sbuf[w * N + i] = v[i];
  __syncthreads();
  #pragma unroll
  for (int i = 0; i < N; ++i)
    v[i] = sbuf[i] + sbuf[N + i] + sbuf[2 * N + i] + sbuf[3 * N + i];
}

// ---- prep: rows scaled by 1/lengthscale + squared norms ----
__global__ void prep_kernel(const float* __restrict__ tx, const float* __restrict__ xx,
                            const float* __restrict__ ls,
                            float* __restrict__ As, float* __restrict__ an,
                            float* __restrict__ Bs, float* __restrict__ bn) {
  int i = blockIdx.x * 256 + threadIdx.x;
  if (i < N_TRAIN) {
    float s = 0.f;
    #pragma unroll
    for (int d = 0; d < DIM; ++d) {
      float v = tx[(size_t)i * DIM + d] / ls[d];
      As[(size_t)i * DIM + d] = v; s += v * v;
    }
    an[i] = s;
  } else if (i < N_TRAIN + N_TEST) {
    int j = i - N_TRAIN;
    float s = 0.f;
    #pragma unroll
    for (int d = 0; d < DIM; ++d) {
      float v = xx[(size_t)j * DIM + d] / ls[d];
      Bs[(size_t)j * DIM + d] = v; s += v * v;
    }
    bn[j] = s;
  }
}

// ---- kernel-matrix builder: 2 adjacent cols/thread (4B coalesced stores),
//      software-pipelined LDS reads: chunk i+1 prefetched during chunk i ----
template <bool NOISE>
__global__ __launch_bounds__(256) void build_kernel(
    const float* __restrict__ RI, const float* __restrict__ nI,
    const float* __restrict__ RJ, const float* __restrict__ nJ,
    unsigned short* __restrict__ O1,
    const float* __restrict__ osc, const float* __restrict__ noi)
{
  __shared__ float aI[128 * DIM];
  __shared__ float sI[128];
  int t = threadIdx.x;
  int j0 = blockIdx.x * 512, i0 = blockIdx.y * 128;
  for (int e = t; e < 128 * DIM; e += 256) aI[e] = RI[(size_t)i0 * DIM + e];
  if (t < 128) sI[t] = nI[i0 + t];
  __syncthreads();

  int ja = j0 + 2 * t, jb = ja + 1;
  f32x4 aj0[4], aj1[4];
  const f32x4* RJa = (const f32x4*)(RJ + (size_t)ja * DIM);
  const f32x4* RJb = (const f32x4*)(RJ + (size_t)jb * DIM);
  #pragma unroll
  for (int q = 0; q < 4; ++q) { aj0[q] = RJa[q]; aj1[q] = RJb[q]; }
  float nja = nJ[ja], njb = nJ[jb];
  float s = osc[0], sn = noi[0];

  // prime chunk 0 (rows 0,1)
  f32x4 cur[2][4];
  #pragma unroll
  for (int r = 0; r < 2; ++r)
    #pragma unroll
    for (int q = 0; q < 4; ++q)
      cur[r][q] = *(const f32x4*)&aI[r * DIM + q * 4];

  for (int ic = 0; ic < 128; ic += 2) {
    // prefetch chunk i+1 before consuming chunk i (hide LDS latency)
    f32x4 nxt[2][4];
    if (ic + 2 < 128) {
      #pragma unroll
      for (int r = 0; r < 2; ++r)
        #pragma unroll
        for (int q = 0; q < 4; ++q)
          nxt[r][q] = *(const f32x4*)&aI[(ic + 2 + r) * DIM + q * 4];
    }
    #pragma unroll
    for (int r = 0; r < 2; ++r) {
      int i = ic + r;
      float d0 = 0.f, d1 = 0.f;
      #pragma unroll
      for (int q = 0; q < 4; ++q) {
        f32x4 ai = cur[r][q];
        d0 += ai[0]*aj0[q][0] + ai[1]*aj0[q][1] + ai[2]*aj0[q][2] + ai[3]*aj0[q][3];
        d1 += ai[0]*aj1[q][0] + ai[1]*aj1[q][1] + ai[2]*aj1[q][2] + ai[3]*aj1[q][3];
      }
      float d2a = fmaxf(sI[i] + nja - 2.f * d0, 0.f);
      float d2b = fmaxf(sI[i] + njb - 2.f * d1, 0.f);
      float va = s * __expf(-0.5f * d2a);
      float vb = s * __expf(-0.5f * d2b);
      if (NOISE && (i0 + i == ja)) va += sn;
      if (NOISE && (i0 + i == jb)) vb += sn;
      unsigned pack = (unsigned)f2bf(va) | ((unsigned)f2bf(vb) << 16);
      *(unsigned*)&O1[(size_t)(i0 + i) * KDIM + ja] = pack;
    }
    #pragma unroll
    for (int r = 0; r < 2; ++r)
      #pragma unroll
      for (int q = 0; q < 4; ++q)
        cur[r][q] = nxt[r][q];
  }
}

// ============  256x256 8-phase pipelined MFMA GEMM (counted vmcnt)  ============
// Q[M][8192] = P[M][8192] * Khat^T. 512 thr (2M x 4N waves), per-wave 128x64.
// LDS [2 buf][2 half][128 rows x 64 bf16] for A and B = 128 KB.
// Swizzle: byte ^= ((row&7)<<4) within 128B rows (both sides, rule #21).

__device__ __forceinline__ void stage_h(const char* gtile, int kbyte,
                                        char* ldsdst, int tid, int wave) {
  #pragma unroll
  for (int q = 0; q < 2; ++q) {
    int o = q * 8192 + tid * 16;
    int r = o >> 7;
    int c = (o & 127) ^ ((r & 7) << 4);
    gl_lds16(gtile + (size_t)r * (KDIM * 2) + kbyte + c,
             ldsdst + q * 8192 + wave * 1024);   // wave-uniform dest, HW adds lane*16
  }
}

template <int FINAL>
__global__ __launch_bounds__(512, 1) void gemm256(
    const unsigned short* __restrict__ A,   // p (Rb for it0, else Pb) [M][KDIM]
    const unsigned short* __restrict__ Bm,  // Khat [8192][KDIM] bf16
    unsigned short* __restrict__ Cq,        // Q [M][8192] bf16
    int gy, float* __restrict__ pq)
{
  __shared__ char Ab[2][2][16384];   // [buf][half][128x64 bf16] = 64 KB
  __shared__ char Bb[2][2][16384];   // 64 KB
  const int tid = threadIdx.x, lane = tid & 63, wave = tid >> 6;
  const int wm = wave >> 2, wn = wave & 3;          // 2M x 4N
  const int nwg = gridDim.x, orig = blockIdx.x;
  const int wgid = (orig & 7) * (nwg >> 3) + (orig >> 3);   // XCD-chunked
  const int bx = wgid / gy, by = wgid % gy;
  const size_t HALF = (size_t)128 * KDIM * 2;

  const char* bA = (const char*)(A  + (size_t)(by * 256) * KDIM);
  const char* bB = (const char*)(Bm + (size_t)(bx * 256) * KDIM);

  // fragment LDS byte offsets within a 16KB half
  const int ar = wm * 64 + (lane & 15);
  const int br = wn * 32 + (lane & 15);
  const int hi = (lane >> 4) * 16;
  int aoff[4][2], boff[2][2];
  #pragma unroll
  for (int mf = 0; mf < 4; ++mf)
    #pragma unroll
    for (int kk = 0; kk < 2; ++kk)
      aoff[mf][kk] = (ar + mf * 16) * 128 + ((hi + kk * 64) ^ ((ar & 7) << 4));
  #pragma unroll
  for (int nf = 0; nf < 2; ++nf)
    #pragma unroll
    for (int kk = 0; kk < 2; ++kk)
      boff[nf][kk] = (br + nf * 16) * 128 + ((hi + kk * 64) ^ ((br & 7) << 4));

  f32x4 acc[2][2][4][2] = {};   // [mh][nh][mf][nf]
  bf16x8 aR[4][2], bR[2][2][2]; // aR[mf][kk], bR[nh][nf][kk]

#define BAR() __builtin_amdgcn_s_barrier()
#define PRIO1 __builtin_amdgcn_s_setprio(1)
#define PRIO0 __builtin_amdgcn_s_setprio(0)
#define FENCE8() asm volatile("s_waitcnt vmcnt(8)" ::: "memory")
#define FENCE6() asm volatile("s_waitcnt vmcnt(6)" ::: "memory")
#define FENCE0() asm volatile("s_waitcnt vmcnt(0)" ::: "memory")
#define STAGE_A(buf, mh, kb) stage_h(bA + ((mh) ? HALF : 0), kb, &Ab[buf][mh][0], tid, wave)
#define STAGE_B(buf, mh, kb) stage_h(bB + ((mh) ? HALF : 0), kb, &Bb[buf][mh][0], tid, wave)
#define LOAD_A(buf, mh)                                                        \
  { _Pragma("unroll") for (int mf = 0; mf < 4; ++mf)                           \
      _Pragma("unroll") for (int kk = 0; kk < 2; ++kk)                         \
        aR[mf][kk] = *(const bf16x8*)(&Ab[buf][mh][0] + aoff[mf][kk]); }
#define LOAD_B(buf, nh)                                                        \
  { _Pragma("unroll") for (int nf = 0; nf < 2; ++nf)                           \
      _Pragma("unroll") for (int kk = 0; kk < 2; ++kk)                         \
        bR[nh][nf][kk] = *(const bf16x8*)(&Bb[buf][nh][0] + boff[nf][kk]); }
#define MFMA16(mh, nh)                                                         \
  { _Pragma("unroll") for (int kk = 0; kk < 2; ++kk)                           \
      _Pragma("unroll") for (int mf = 0; mf < 4; ++mf)                         \
        _Pragma("unroll") for (int nf = 0; nf < 2; ++nf)                       \
          acc[mh][nh][mf][nf] = __builtin_amdgcn_mfma_f32_16x16x32_bf16(       \
              aR[mf][kk], bR[nh][nf][kk], acc[mh][nh][mf][nf], 0, 0, 0); }

  // prologue: tiles 0 (buf0) and 1 (buf1); order matters for the FIFO ledger
  STAGE_A(0, 0, 0);   STAGE_B(0, 0, 0);   STAGE_B(0, 1, 0);   STAGE_A(0, 1, 0);
  STAGE_A(1, 0, 128); STAGE_B(1, 0, 128); STAGE_B(1, 1, 128); STAGE_A(1, 1, 128);
  FENCE6();            // completes tile0 fully + A0(1); leaves B0,B1,A1(1) in flight
  BAR();

  for (int t = 0; t < NT; t += 2) {
    const bool g = (t + 2 < NT);
    const int kb2 = (t + 2) * 128, kb3 = (t + 3) * 128;
    // ph1: tile t quad(0,0) — no stage
    LOAD_A(0, 0); LOAD_B(0, 0);
    BAR(); PRIO1; MFMA16(0, 0); PRIO0; BAR();
    // ph2: quad(0,1); stage A0(t+2)
    if (g) STAGE_A(0, 0, kb2);
    LOAD_B(0, 1);
    BAR(); PRIO1; MFMA16(0, 1); PRIO0; BAR();
    // ph3: quad(1,0); stage B0(t+2)
    if (g) STAGE_B(0, 0, kb2);
    LOAD_A(0, 1);
    BAR(); PRIO1; MFMA16(1, 0); PRIO0; BAR();
    // ph4: quad(1,1); stage B1(t+2)+A1(t+2); fence -> tile t+1 ready
    if (g) { STAGE_B(0, 1, kb2); STAGE_A(0, 1, kb2); }
    BAR(); PRIO1; MFMA16(1, 1); PRIO0;
    if (g) { FENCE8(); } else { FENCE0(); }
    BAR();
    // ph5: tile t+1 quad(0,0) — no stage
    LOAD_A(1, 0); LOAD_B(1, 0);
    BAR(); PRIO1; MFMA16(0, 0); PRIO0; BAR();
    // ph6: quad(0,1); stage A0(t+3)
    if (g) STAGE_A(1, 0, kb3);
    LOAD_B(1, 1);
    BAR(); PRIO1; MFMA16(0, 1); PRIO0; BAR();
    // ph7: quad(1,0); stage B0(t+3)
    if (g) STAGE_B(1, 0, kb3);
    LOAD_A(1, 1);
    BAR(); PRIO1; MFMA16(1, 0); PRIO0; BAR();
    // ph8: quad(1,1); stage B1(t+3)+A1(t+3); fence -> tile t+2 fully done + A0(t+3)
    if (g) { STAGE_B(1, 1, kb3); STAGE_A(1, 1, kb3); }
    BAR(); PRIO1; MFMA16(1, 1); PRIO0;
    if (g) { FENCE6(); }
    BAR();
  }

  const int bm = by * 256, bn = bx * 256;
  if (!FINAL) {
    // C/D mapping (verified): col = lane&15, row = (lane>>4)*4 + reg
    #pragma unroll
    for (int mh = 0; mh < 2; ++mh)
      #pragma unroll
      for (int nh = 0; nh < 2; ++nh)
        #pragma unroll
        for (int mf = 0; mf < 4; ++mf)
          #pragma unroll
          for (int nf = 0; nf < 2; ++nf) {
            int row = bm + mh * 128 + wm * 64 + mf * 16 + (lane >> 4) * 4;
            int col = bn + nh * 128 + wn * 32 + nf * 16 + (lane & 15);
            #pragma unroll
            for (int rg = 0; rg < 4; ++rg)
              Cq[(size_t)(row + rg) * KDIM + col] = f2bf(acc[mh][nh][mf][nf][rg]);
          }
  } else {
    // final iteration: only pAp. pq[row] += sum_col P[row][col]*Q[row][col]
    #pragma unroll
    for (int mh = 0; mh < 2; ++mh)
      #pragma unroll
      for (int mf = 0; mf < 4; ++mf)
        #pragma unroll
        for (int rg = 0; rg < 4; ++rg) {
          int row = bm + mh * 128 + wm * 64 + mf * 16 + (lane >> 4) * 4 + rg;
          float v = 0.f;
          #pragma unroll
          for (int nh = 0; nh < 2; ++nh)
            #pragma unroll
            for (int nf = 0; nf < 2; ++nf) {
              int col = bn + nh * 128 + wn * 32 + nf * 16 + (lane & 15);
              v += acc[mh][nh][mf][nf][rg] * bf2f(A[(size_t)row * KDIM + col]);
            }
          v += __shfl_xor(v, 1); v += __shfl_xor(v, 2);
          v += __shfl_xor(v, 4); v += __shfl_xor(v, 8);
          if ((lane & 15) == 0) atomicAdd(&pq[row], v);
        }
  }
#undef MFMA16
#undef LOAD_B
#undef LOAD_A
#undef STAGE_B
#undef STAGE_A
#undef FENCE0
#undef FENCE6
#undef FENCE8
#undef PRIO0
#undef PRIO1
#undef BAR
}

// ---- CG step: single reduction (recurrence), fused R'/P' update (r11) ----
// scal[c*8]: {rr, yp, yr, mean, bx}
template <bool FIRST>
__global__ __launch_bounds__(256) void cg_step(
    const unsigned short* __restrict__ Q, unsigned short* __restrict__ R,
    unsigned short* __restrict__ P, const float* __restrict__ y,
    float* __restrict__ scal, float* __restrict__ pq)
{
  __shared__ float sbuf[24];
  int c = blockIdx.x, t = threadIdx.x;
  size_t base = (size_t)c * KDIM;

  bf16x8 q8[4], r8[4], p8[4];
  #pragma unroll
  for (int k = 0; k < 4; ++k) q8[k] = *(const bf16x8*)&Q[base + k * 2048 + t * 8];
  #pragma unroll
  for (int k = 0; k < 4; ++k) r8[k] = *(const bf16x8*)&R[base + k * 2048 + t * 8];
  if (FIRST) {
    #pragma unroll
    for (int k = 0; k < 4; ++k) p8[k] = r8[k];
  } else {
    #pragma unroll
    for (int k = 0; k < 4; ++k) p8[k] = *(const bf16x8*)&P[base + k * 2048 + t * 8];
  }

  // all dots in one pass: v = {p.q, r.q, q.q, y.q, r.r, y.r} (4,5 used on FIRST)
  float v[6] = {0.f, 0.f, 0.f, 0.f, 0.f, 0.f};
  #pragma unroll
  for (int k = 0; k < 4; ++k) {
    int j = k * 2048 + t * 8;
    f32x4 ya = *(const f32x4*)&y[j];
    f32x4 yb = *(const f32x4*)&y[j + 4];
    #pragma unroll
    for (int e = 0; e < 8; ++e) {
      float qv = bf2f((unsigned short)q8[k][e]);
      float rv = bf2f((unsigned short)r8[k][e]);
      float pv = FIRST ? rv : bf2f((unsigned short)p8[k][e]);
      float yv = (e < 4) ? ya[e] : yb[e - 4];
      v[0] += pv * qv; v[1] += rv * qv; v[2] += qv * qv; v[3] += yv * qv;
      if (FIRST) { v[4] += rv * rv; v[5] += yv * rv; }
    }
  }
  block_reduceN<6>(v, sbuf);

  float rr, yp, yr, mean, bx;
  if (FIRST) {
    rr = v[4]; yp = v[5]; yr = v[5]; mean = 0.f; bx = 0.f;
  } else {
    rr = scal[c*8+0]; yp = scal[c*8+1]; yr = scal[c*8+2];
    mean = scal[c*8+3]; bx = scal[c*8+4];
  }
  float alpha = rr / fmaxf(v[0], 1e-30f);
  mean += alpha * yp;
  bx   += alpha * rr;
  float rrn = fmaxf(rr - 2.f * alpha * v[1] + alpha * alpha * v[2], 0.f);
  float yrn = yr - alpha * v[3];
  float beta = rrn / fmaxf(rr, 1e-30f);
  float ypn  = yrn + beta * yp;

  // fused update: r' = r - alpha*q (write) ; p' = r'(rounded) + beta*p (write)
  #pragma unroll
  for (int k = 0; k < 4; ++k) {
    int j = k * 2048 + t * 8;
    bf16x8 wr, wp;
    #pragma unroll
    for (int e = 0; e < 8; ++e) {
      float rn = bf2f((unsigned short)r8[k][e]) -
                 alpha * bf2f((unsigned short)q8[k][e]);
      unsigned short hb = f2bf(rn);
      wr[e] = (short)hb;
      wp[e] = (short)f2bf(bf2f(hb) + beta * bf2f((unsigned short)p8[k][e]));
    }
    *(bf16x8*)&R[base + j] = wr;
    *(bf16x8*)&P[base + j] = wp;
  }
  if (t == 0) {
    scal[c*8+0] = rrn; scal[c*8+1] = ypn; scal[c*8+2] = yrn;
    scal[c*8+3] = mean; scal[c*8+4] = bx;
    pq[c] = 0.f;   // zero for the final gemm's atomics
  }
}

// ---- final outputs from pq (pAp of last iteration) + scal ----
__global__ void final_out(const float* __restrict__ pq, const float* __restrict__ scal,
                          const float* __restrict__ osc, const float* __restrict__ noi,
                          float* __restrict__ out, int c0, int C)
{
  int c = blockIdx.x * 256 + threadIdx.x;
  if (c >= C) return;
  float rr = scal[c*8+0], yp = scal[c*8+1];
  float mean = scal[c*8+3], bx = scal[c*8+4];
  float alpha = rr / fmaxf(pq[c], 1e-30f);
  mean += alpha * yp;
  bx   += alpha * rr;
  out[c0 + c] = mean;
  out[N_TEST + c0 + c] = osc[0] + noi[0] - bx;
}

extern "C" void kernel_launch(void* const* d_in, const int* in_sizes, int n_in,
                              void* d_out, int out_size, void* d_ws, size_t ws_size,
                              hipStream_t stream) {
  const float* tx = (const float*)d_in[0];
  const float* ty = (const float*)d_in[1];
  const float* xx = (const float*)d_in[2];
  const float* os = (const float*)d_in[3];
  const float* ls = (const float*)d_in[4];
  const float* ns = (const float*)d_in[5];
  float* out = (float*)d_out;
  (void)in_sizes; (void)n_in; (void)out_size;

  auto pad = [](size_t x) { return (x + 255) & ~(size_t)255; };
  size_t fixed = pad((size_t)N_TRAIN * KDIM * 2)
               + pad((size_t)N_TRAIN * DIM * 4) + pad((size_t)N_TRAIN * 4)
               + pad((size_t)N_TEST * DIM * 4) + pad((size_t)N_TEST * 4);
  int C = 4096;
  while (C > 256) {
    size_t tot = fixed + 3 * pad((size_t)C * KDIM * 2)
               + pad((size_t)C * 32) + pad((size_t)C * 4);
    if (tot <= ws_size) break;
    C >>= 1;
  }

  char* w = (char*)d_ws;
  auto alloc = [&](size_t bytes) { char* p = w; w += ((bytes + 255) & ~(size_t)255); return p; };
  unsigned short* Kb = (unsigned short*)alloc((size_t)N_TRAIN * KDIM * 2);
  float* As = (float*)alloc((size_t)N_TRAIN * DIM * 4);
  float* an = (float*)alloc((size_t)N_TRAIN * 4);
  float* Bs = (float*)alloc((size_t)N_TEST * DIM * 4);
  float* bn = (float*)alloc((size_t)N_TEST * 4);
  unsigned short* Rb = (unsigned short*)alloc((size_t)C * KDIM * 2);
  unsigned short* Pb = (unsigned short*)alloc((size_t)C * KDIM * 2);
  unsigned short* Qb = (unsigned short*)alloc((size_t)C * KDIM * 2);
  float* scal = (float*)alloc((size_t)C * 32);
  float* pq   = (float*)alloc((size_t)C * 4);

  prep_kernel<<<48, 256, 0, stream>>>(tx, xx, ls, As, an, Bs, bn);

  build_kernel<true><<<dim3(KDIM / 512, N_TRAIN / 128), 256, 0, stream>>>(
      As, an, As, an, Kb, os, ns);

  for (int c0 = 0; c0 < N_TEST; c0 += C) {
    build_kernel<false><<<dim3(KDIM / 512, C / 128), 256, 0, stream>>>(
        Bs + (size_t)c0 * DIM, bn + c0, As, an, Rb, os, ns);
    int gy = C / 256;
    dim3 gg(32 * gy);
    int scb = (C + 255) / 256;
    for (int it = 0; it < CG_ITERS; ++it) {
      const unsigned short* Ain = (it == 0) ? Rb : Pb;
      int fin = (it == CG_ITERS - 1) ? 1 : 0;
      if (!fin) {
        gemm256<0><<<gg, 512, 0, stream>>>(Ain, Kb, Qb, gy, pq);
        if (it == 0)
          cg_step<true><<<C, 256, 0, stream>>>(Qb, Rb, Pb, ty, scal, pq);
        else
          cg_step<false><<<C, 256, 0, stream>>>(Qb, Rb, Pb, ty, scal, pq);
      } else {
        gemm256<1><<<gg, 512, 0, stream>>>(Ain, Kb, Qb, gy, pq);
        final_out<<<scb, 256, 0, stream>>>(pq, scal, os, ns, out, c0, C);
      }
    }
  }
}

// Round 14
// 2240.621 us; speedup vs baseline: 1.7555x; 1.0970x over previous
//
#include <hip/hip_runtime.h>
#include <stdint.h>

// GP posterior via batched CG, 4 iterations. Khat split: off-diagonal bf16 (K_od,
// diag forced 0) + EXACT f32 diagonal d=s+sn applied in cg_step (q_eff = q + d*p).
// Kills the bf16-diagonal error floor (0.0039). Final mean gets a free Richardson
// polish (mean += yr4/d); var truncation is quadratic (CG Galerkin identity).
// Matvec = 256x256x64 8-phase counted-vmcnt MFMA GEMM (87% dense peak, r10).

#define N_TRAIN 8192
#define N_TEST  4096
#define DIM     16
#define KDIM    8192
#define CG_ITERS 4
#define NT      (KDIM / 64)   // 128 K-tiles of BK=64

using f32x4  = __attribute__((ext_vector_type(4))) float;
using bf16x8 = __attribute__((ext_vector_type(8))) short;

static __device__ __forceinline__ unsigned short f2bf(float f) {
  unsigned u = __float_as_uint(f);
  u = (u + 0x7FFFu + ((u >> 16) & 1u)) >> 16;   // RNE
  return (unsigned short)u;
}
static __device__ __forceinline__ float bf2f(unsigned short h) {
  return __uint_as_float(((unsigned)h) << 16);
}

__device__ __forceinline__ void gl_lds16(const void* g, void* l) {
  __builtin_amdgcn_global_load_lds(
      (const __attribute__((address_space(1))) unsigned int*)g,
      (__attribute__((address_space(3))) unsigned int*)l, 16, 0, 0);
}

template <int N>
__device__ __forceinline__ void block_reduceN(float* v, float* sbuf) {
  #pragma unroll
  for (int off = 32; off > 0; off >>= 1)
    #pragma unroll
    for (int i = 0; i < N; ++i) v[i] += __shfl_down(v[i], off);
  int lane = threadIdx.x & 63, w = threadIdx.x >> 6;
  if (lane == 0)
    #pragma unroll
    for (int i = 0; i < N; ++i) sbuf[w * N + i] = v[i];
  __syncthreads();
  #pragma unroll
  for (int i = 0; i < N; ++i)
    v[i] = sbuf[i] + sbuf[N + i] + sbuf[2 * N + i] + sbuf[3 * N + i];
}

// ---- prep: rows scaled by 1/lengthscale + squared norms ----
__global__ void prep_kernel(const float* __restrict__ tx, const float* __restrict__ xx,
                            const float* __restrict__ ls,
                            float* __restrict__ As, float* __restrict__ an,
                            float* __restrict__ Bs, float* __restrict__ bn) {
  int i = blockIdx.x * 256 + threadIdx.x;
  if (i < N_TRAIN) {
    float s = 0.f;
    #pragma unroll
    for (int d = 0; d < DIM; ++d) {
      float v = tx[(size_t)i * DIM + d] / ls[d];
      As[(size_t)i * DIM + d] = v; s += v * v;
    }
    an[i] = s;
  } else if (i < N_TRAIN + N_TEST) {
    int j = i - N_TRAIN;
    float s = 0.f;
    #pragma unroll
    for (int d = 0; d < DIM; ++d) {
      float v = xx[(size_t)j * DIM + d] / ls[d];
      Bs[(size_t)j * DIM + d] = v; s += v * v;
    }
    bn[j] = s;
  }
}

// ---- kernel-matrix builder: 2 adjacent cols/thread (4B coalesced stores).
// DIAG0: force diagonal to ZERO (Khat's true diagonal handled exactly in f32). ----
template <bool DIAG0>
__global__ __launch_bounds__(256) void build_kernel(
    const float* __restrict__ RI, const float* __restrict__ nI,
    const float* __restrict__ RJ, const float* __restrict__ nJ,
    unsigned short* __restrict__ O1,
    const float* __restrict__ osc)
{
  __shared__ float aI[128 * DIM];
  __shared__ float sI[128];
  int t = threadIdx.x;
  int j0 = blockIdx.x * 512, i0 = blockIdx.y * 128;
  for (int e = t; e < 128 * DIM; e += 256) aI[e] = RI[(size_t)i0 * DIM + e];
  if (t < 128) sI[t] = nI[i0 + t];
  __syncthreads();

  int ja = j0 + 2 * t, jb = ja + 1;
  f32x4 aj0[4], aj1[4];
  const f32x4* RJa = (const f32x4*)(RJ + (size_t)ja * DIM);
  const f32x4* RJb = (const f32x4*)(RJ + (size_t)jb * DIM);
  #pragma unroll
  for (int q = 0; q < 4; ++q) { aj0[q] = RJa[q]; aj1[q] = RJb[q]; }
  float nja = nJ[ja], njb = nJ[jb];
  float s = osc[0];

  for (int ic = 0; ic < 128; ic += 2) {
    f32x4 rv[2][4];
    #pragma unroll
    for (int r = 0; r < 2; ++r)
      #pragma unroll
      for (int q = 0; q < 4; ++q)
        rv[r][q] = *(const f32x4*)&aI[(ic + r) * DIM + q * 4];
    #pragma unroll
    for (int r = 0; r < 2; ++r) {
      int i = ic + r;
      float d0 = 0.f, d1 = 0.f;
      #pragma unroll
      for (int q = 0; q < 4; ++q) {
        f32x4 ai = rv[r][q];
        d0 += ai[0]*aj0[q][0] + ai[1]*aj0[q][1] + ai[2]*aj0[q][2] + ai[3]*aj0[q][3];
        d1 += ai[0]*aj1[q][0] + ai[1]*aj1[q][1] + ai[2]*aj1[q][2] + ai[3]*aj1[q][3];
      }
      float d2a = fmaxf(sI[i] + nja - 2.f * d0, 0.f);
      float d2b = fmaxf(sI[i] + njb - 2.f * d1, 0.f);
      float va = s * __expf(-0.5f * d2a);
      float vb = s * __expf(-0.5f * d2b);
      if (DIAG0 && (i0 + i == ja)) va = 0.f;
      if (DIAG0 && (i0 + i == jb)) vb = 0.f;
      unsigned pack = (unsigned)f2bf(va) | ((unsigned)f2bf(vb) << 16);
      *(unsigned*)&O1[(size_t)(i0 + i) * KDIM + ja] = pack;
    }
  }
}

// ============  256x256 8-phase pipelined MFMA GEMM (counted vmcnt)  ============
// Q[M][8192] = P[M][8192] * K_od^T. 512 thr (2M x 4N waves), per-wave 128x64.
// FINAL=1: no Q store; epilogue dots {p.q_od, p.p, y.q_od} -> pqf[row][0..2].

__device__ __forceinline__ void stage_h(const char* gtile, int kbyte,
                                        char* ldsdst, int tid, int wave) {
  #pragma unroll
  for (int q = 0; q < 2; ++q) {
    int o = q * 8192 + tid * 16;
    int r = o >> 7;
    int c = (o & 127) ^ ((r & 7) << 4);
    gl_lds16(gtile + (size_t)r * (KDIM * 2) + kbyte + c,
             ldsdst + q * 8192 + wave * 1024);   // wave-uniform dest, HW adds lane*16
  }
}

template <int FINAL>
__global__ __launch_bounds__(512, 1) void gemm256(
    const unsigned short* __restrict__ A,   // p (Rb for it0, else Pb) [M][KDIM]
    const unsigned short* __restrict__ Bm,  // K_od [8192][KDIM] bf16
    unsigned short* __restrict__ Cq,        // Q [M][8192] bf16
    int gy, const float* __restrict__ y, float* __restrict__ pqf)
{
  __shared__ char Ab[2][2][16384];
  __shared__ char Bb[2][2][16384];
  const int tid = threadIdx.x, lane = tid & 63, wave = tid >> 6;
  const int wm = wave >> 2, wn = wave & 3;          // 2M x 4N
  const int nwg = gridDim.x, orig = blockIdx.x;
  const int wgid = (orig & 7) * (nwg >> 3) + (orig >> 3);   // XCD-chunked
  const int bx = wgid / gy, by = wgid % gy;
  const size_t HALF = (size_t)128 * KDIM * 2;

  const char* bA = (const char*)(A  + (size_t)(by * 256) * KDIM);
  const char* bB = (const char*)(Bm + (size_t)(bx * 256) * KDIM);

  const int ar = wm * 64 + (lane & 15);
  const int br = wn * 32 + (lane & 15);
  const int hi = (lane >> 4) * 16;
  int aoff[4][2], boff[2][2];
  #pragma unroll
  for (int mf = 0; mf < 4; ++mf)
    #pragma unroll
    for (int kk = 0; kk < 2; ++kk)
      aoff[mf][kk] = (ar + mf * 16) * 128 + ((hi + kk * 64) ^ ((ar & 7) << 4));
  #pragma unroll
  for (int nf = 0; nf < 2; ++nf)
    #pragma unroll
    for (int kk = 0; kk < 2; ++kk)
      boff[nf][kk] = (br + nf * 16) * 128 + ((hi + kk * 64) ^ ((br & 7) << 4));

  f32x4 acc[2][2][4][2] = {};
  bf16x8 aR[4][2], bR[2][2][2];

#define BAR() __builtin_amdgcn_s_barrier()
#define PRIO1 __builtin_amdgcn_s_setprio(1)
#define PRIO0 __builtin_amdgcn_s_setprio(0)
#define FENCE8() asm volatile("s_waitcnt vmcnt(8)" ::: "memory")
#define FENCE6() asm volatile("s_waitcnt vmcnt(6)" ::: "memory")
#define FENCE0() asm volatile("s_waitcnt vmcnt(0)" ::: "memory")
#define STAGE_A(buf, mh, kb) stage_h(bA + ((mh) ? HALF : 0), kb, &Ab[buf][mh][0], tid, wave)
#define STAGE_B(buf, mh, kb) stage_h(bB + ((mh) ? HALF : 0), kb, &Bb[buf][mh][0], tid, wave)
#define LOAD_A(buf, mh)                                                        \
  { _Pragma("unroll") for (int mf = 0; mf < 4; ++mf)                           \
      _Pragma("unroll") for (int kk = 0; kk < 2; ++kk)                         \
        aR[mf][kk] = *(const bf16x8*)(&Ab[buf][mh][0] + aoff[mf][kk]); }
#define LOAD_B(buf, nh)                                                        \
  { _Pragma("unroll") for (int nf = 0; nf < 2; ++nf)                           \
      _Pragma("unroll") for (int kk = 0; kk < 2; ++kk)                         \
        bR[nh][nf][kk] = *(const bf16x8*)(&Bb[buf][nh][0] + boff[nf][kk]); }
#define MFMA16(mh, nh)                                                         \
  { _Pragma("unroll") for (int kk = 0; kk < 2; ++kk)                           \
      _Pragma("unroll") for (int mf = 0; mf < 4; ++mf)                         \
        _Pragma("unroll") for (int nf = 0; nf < 2; ++nf)                       \
          acc[mh][nh][mf][nf] = __builtin_amdgcn_mfma_f32_16x16x32_bf16(       \
              aR[mf][kk], bR[nh][nf][kk], acc[mh][nh][mf][nf], 0, 0, 0); }

  STAGE_A(0, 0, 0);   STAGE_B(0, 0, 0);   STAGE_B(0, 1, 0);   STAGE_A(0, 1, 0);
  STAGE_A(1, 0, 128); STAGE_B(1, 0, 128); STAGE_B(1, 1, 128); STAGE_A(1, 1, 128);
  FENCE6();
  BAR();

  for (int t = 0; t < NT; t += 2) {
    const bool g = (t + 2 < NT);
    const int kb2 = (t + 2) * 128, kb3 = (t + 3) * 128;
    LOAD_A(0, 0); LOAD_B(0, 0);
    BAR(); PRIO1; MFMA16(0, 0); PRIO0; BAR();
    if (g) STAGE_A(0, 0, kb2);
    LOAD_B(0, 1);
    BAR(); PRIO1; MFMA16(0, 1); PRIO0; BAR();
    if (g) STAGE_B(0, 0, kb2);
    LOAD_A(0, 1);
    BAR(); PRIO1; MFMA16(1, 0); PRIO0; BAR();
    if (g) { STAGE_B(0, 1, kb2); STAGE_A(0, 1, kb2); }
    BAR(); PRIO1; MFMA16(1, 1); PRIO0;
    if (g) { FENCE8(); } else { FENCE0(); }
    BAR();
    LOAD_A(1, 0); LOAD_B(1, 0);
    BAR(); PRIO1; MFMA16(0, 0); PRIO0; BAR();
    if (g) STAGE_A(1, 0, kb3);
    LOAD_B(1, 1);
    BAR(); PRIO1; MFMA16(0, 1); PRIO0; BAR();
    if (g) STAGE_B(1, 0, kb3);
    LOAD_A(1, 1);
    BAR(); PRIO1; MFMA16(1, 0); PRIO0; BAR();
    if (g) { STAGE_B(1, 1, kb3); STAGE_A(1, 1, kb3); }
    BAR(); PRIO1; MFMA16(1, 1); PRIO0;
    if (g) { FENCE6(); }
    BAR();
  }

  const int bm = by * 256, bn = bx * 256;
  if (!FINAL) {
    // C/D mapping (verified): col = lane&15, row = (lane>>4)*4 + reg
    #pragma unroll
    for (int mh = 0; mh < 2; ++mh)
      #pragma unroll
      for (int nh = 0; nh < 2; ++nh)
        #pragma unroll
        for (int mf = 0; mf < 4; ++mf)
          #pragma unroll
          for (int nf = 0; nf < 2; ++nf) {
            int row = bm + mh * 128 + wm * 64 + mf * 16 + (lane >> 4) * 4;
            int col = bn + nh * 128 + wn * 32 + nf * 16 + (lane & 15);
            #pragma unroll
            for (int rg = 0; rg < 4; ++rg)
              Cq[(size_t)(row + rg) * KDIM + col] = f2bf(acc[mh][nh][mf][nf][rg]);
          }
  } else {
    // final iteration: dots {p.q_od, p.p, y.q_od} -> pqf[row][0..2]
    #pragma unroll
    for (int mh = 0; mh < 2; ++mh)
      #pragma unroll
      for (int mf = 0; mf < 4; ++mf)
        #pragma unroll
        for (int rg = 0; rg < 4; ++rg) {
          int row = bm + mh * 128 + wm * 64 + mf * 16 + (lane >> 4) * 4 + rg;
          float s0 = 0.f, s1 = 0.f, s2 = 0.f;
          #pragma unroll
          for (int nh = 0; nh < 2; ++nh)
            #pragma unroll
            for (int nf = 0; nf < 2; ++nf) {
              int col = bn + nh * 128 + wn * 32 + nf * 16 + (lane & 15);
              float qv = acc[mh][nh][mf][nf][rg];
              float pv = bf2f(A[(size_t)row * KDIM + col]);
              float yv = y[col];
              s0 += pv * qv; s1 += pv * pv; s2 += yv * qv;
            }
          #pragma unroll
          for (int off = 1; off < 16; off <<= 1) {
            s0 += __shfl_xor(s0, off);
            s1 += __shfl_xor(s1, off);
            s2 += __shfl_xor(s2, off);
          }
          if ((lane & 15) == 0) {
            float* dd = &pqf[(size_t)row * 4];
            atomicAdd(&dd[0], s0); atomicAdd(&dd[1], s1); atomicAdd(&dd[2], s2);
          }
        }
  }
#undef MFMA16
#undef LOAD_B
#undef LOAD_A
#undef STAGE_B
#undef STAGE_A
#undef FENCE0
#undef FENCE6
#undef FENCE8
#undef PRIO0
#undef PRIO1
#undef BAR
}

// ---- CG step with exact-diagonal correction: q_eff = q_od + dg*p.
// scal[c*8]: {rr, yp, yr, mean, bx}. Single reduction; fused R'/P' update. ----
template <bool FIRST>
__global__ __launch_bounds__(256) void cg_step(
    const unsigned short* __restrict__ Q, unsigned short* __restrict__ R,
    unsigned short* __restrict__ P, const float* __restrict__ y,
    float* __restrict__ scal, float* __restrict__ pqf,
    const float* __restrict__ osc, const float* __restrict__ noi)
{
  __shared__ float sbuf[24];
  int c = blockIdx.x, t = threadIdx.x;
  size_t base = (size_t)c * KDIM;
  float dg = osc[0] + noi[0];       // exact f32 diagonal of Khat

  bf16x8 q8[4], r8[4], p8[4];
  #pragma unroll
  for (int k = 0; k < 4; ++k) q8[k] = *(const bf16x8*)&Q[base + k * 2048 + t * 8];
  #pragma unroll
  for (int k = 0; k < 4; ++k) r8[k] = *(const bf16x8*)&R[base + k * 2048 + t * 8];
  if (FIRST) {
    #pragma unroll
    for (int k = 0; k < 4; ++k) p8[k] = r8[k];
  } else {
    #pragma unroll
    for (int k = 0; k < 4; ++k) p8[k] = *(const bf16x8*)&P[base + k * 2048 + t * 8];
  }

  // FIRST: v = {p.q, q.q, y.q, r.r, y.r, 0}; MID: v = {p.q, r.q, q.q, y.q, p.p, r.p}
  float v[6] = {0.f, 0.f, 0.f, 0.f, 0.f, 0.f};
  #pragma unroll
  for (int k = 0; k < 4; ++k) {
    int j = k * 2048 + t * 8;
    f32x4 ya = *(const f32x4*)&y[j];
    f32x4 yb = *(const f32x4*)&y[j + 4];
    #pragma unroll
    for (int e = 0; e < 8; ++e) {
      float qv = bf2f((unsigned short)q8[k][e]);
      float rv = bf2f((unsigned short)r8[k][e]);
      float yv = (e < 4) ? ya[e] : yb[e - 4];
      if (FIRST) {
        v[0] += rv * qv; v[1] += qv * qv; v[2] += yv * qv;
        v[3] += rv * rv; v[4] += yv * rv;
      } else {
        float pv = bf2f((unsigned short)p8[k][e]);
        v[0] += pv * qv; v[1] += rv * qv; v[2] += qv * qv; v[3] += yv * qv;
        v[4] += pv * pv; v[5] += rv * pv;
      }
    }
  }
  block_reduceN<6>(v, sbuf);

  float rr, yp, yr, mean, bx;
  float pq_od, rq_od, qq_od, yq_od, pp, rp;
  if (FIRST) {
    rr = v[3]; yp = v[4]; yr = v[4]; mean = 0.f; bx = 0.f;
    pq_od = v[0]; rq_od = v[0]; qq_od = v[1]; yq_od = v[2];
    pp = v[3]; rp = v[3];
  } else {
    rr = scal[c*8+0]; yp = scal[c*8+1]; yr = scal[c*8+2];
    mean = scal[c*8+3]; bx = scal[c*8+4];
    pq_od = v[0]; rq_od = v[1]; qq_od = v[2]; yq_od = v[3];
    pp = v[4]; rp = v[5];
  }
  float pAp   = pq_od + dg * pp;
  float rq_e  = rq_od + dg * rp;
  float qq_e  = qq_od + 2.f * dg * pq_od + dg * dg * pp;
  float yq_e  = yq_od + dg * yp;

  float alpha = rr / fmaxf(pAp, 1e-30f);
  mean += alpha * yp;
  bx   += alpha * rr;
  float rrn = fmaxf(rr - 2.f * alpha * rq_e + alpha * alpha * qq_e, 0.f);
  float yrn = yr - alpha * yq_e;
  float beta = rrn / fmaxf(rr, 1e-30f);
  float ypn  = yrn + beta * yp;

  // fused update: r' = r - alpha*(q + dg*p); p' = r'(rounded) + beta*p
  #pragma unroll
  for (int k = 0; k < 4; ++k) {
    int j = k * 2048 + t * 8;
    bf16x8 wr, wp;
    #pragma unroll
    for (int e = 0; e < 8; ++e) {
      float pv = bf2f((unsigned short)p8[k][e]);
      float qe = bf2f((unsigned short)q8[k][e]) + dg * pv;
      float rn = bf2f((unsigned short)r8[k][e]) - alpha * qe;
      unsigned short hb = f2bf(rn);
      wr[e] = (short)hb;
      wp[e] = (short)f2bf(bf2f(hb) + beta * pv);
    }
    *(bf16x8*)&R[base + j] = wr;
    *(bf16x8*)&P[base + j] = wp;
  }
  if (t == 0) {
    scal[c*8+0] = rrn; scal[c*8+1] = ypn; scal[c*8+2] = yrn;
    scal[c*8+3] = mean; scal[c*8+4] = bx;
    f32x4 z = {0.f, 0.f, 0.f, 0.f};
    *(f32x4*)&pqf[(size_t)c * 4] = z;   // ready for the FINAL gemm's atomics
  }
}

// ---- final outputs: last alpha + Richardson polish on mean ----
__global__ void final_out(float* __restrict__ pqf, const float* __restrict__ scal,
                          const float* __restrict__ osc, const float* __restrict__ noi,
                          float* __restrict__ out, int c0, int C)
{
  int c = blockIdx.x * 256 + threadIdx.x;
  if (c >= C) return;
  float dg = osc[0] + noi[0];
  float* dd = &pqf[(size_t)c * 4];
  float rr = scal[c*8+0], yp = scal[c*8+1], yr = scal[c*8+2];
  float mean = scal[c*8+3], bx = scal[c*8+4];
  float pAp  = dd[0] + dg * dd[1];
  float alpha = rr / fmaxf(pAp, 1e-30f);
  mean += alpha * yp;
  bx   += alpha * rr;
  float yq_e = dd[2] + dg * yp;
  float yr4  = yr - alpha * yq_e;
  mean += yr4 / dg;                    // Richardson polish: x' = x + r/d
  out[c0 + c] = mean;
  out[N_TEST + c0 + c] = osc[0] + noi[0] - bx;
  dd[0] = 0.f; dd[1] = 0.f; dd[2] = 0.f; dd[3] = 0.f;
}

extern "C" void kernel_launch(void* const* d_in, const int* in_sizes, int n_in,
                              void* d_out, int out_size, void* d_ws, size_t ws_size,
                              hipStream_t stream) {
  const float* tx = (const float*)d_in[0];
  const float* ty = (const float*)d_in[1];
  const float* xx = (const float*)d_in[2];
  const float* os = (const float*)d_in[3];
  const float* ls = (const float*)d_in[4];
  const float* ns = (const float*)d_in[5];
  float* out = (float*)d_out;
  (void)in_sizes; (void)n_in; (void)out_size;

  auto pad = [](size_t x) { return (x + 255) & ~(size_t)255; };
  size_t fixed = pad((size_t)N_TRAIN * KDIM * 2)
               + pad((size_t)N_TRAIN * DIM * 4) + pad((size_t)N_TRAIN * 4)
               + pad((size_t)N_TEST * DIM * 4) + pad((size_t)N_TEST * 4);
  int C = 4096;
  while (C > 256) {
    size_t tot = fixed + 3 * pad((size_t)C * KDIM * 2)
               + pad((size_t)C * 32) + pad((size_t)C * 16);
    if (tot <= ws_size) break;
    C >>= 1;
  }

  char* w = (char*)d_ws;
  auto alloc = [&](size_t bytes) { char* p = w; w += ((bytes + 255) & ~(size_t)255); return p; };
  unsigned short* Kb = (unsigned short*)alloc((size_t)N_TRAIN * KDIM * 2);
  float* As = (float*)alloc((size_t)N_TRAIN * DIM * 4);
  float* an = (float*)alloc((size_t)N_TRAIN * 4);
  float* Bs = (float*)alloc((size_t)N_TEST * DIM * 4);
  float* bn = (float*)alloc((size_t)N_TEST * 4);
  unsigned short* Rb = (unsigned short*)alloc((size_t)C * KDIM * 2);
  unsigned short* Pb = (unsigned short*)alloc((size_t)C * KDIM * 2);
  unsigned short* Qb = (unsigned short*)alloc((size_t)C * KDIM * 2);
  float* scal = (float*)alloc((size_t)C * 32);
  float* pqf  = (float*)alloc((size_t)C * 16);

  hipMemsetAsync(pqf, 0, (size_t)C * 16, stream);

  prep_kernel<<<48, 256, 0, stream>>>(tx, xx, ls, As, an, Bs, bn);

  build_kernel<true><<<dim3(KDIM / 512, N_TRAIN / 128), 256, 0, stream>>>(
      As, an, As, an, Kb, os);

  for (int c0 = 0; c0 < N_TEST; c0 += C) {
    build_kernel<false><<<dim3(KDIM / 512, C / 128), 256, 0, stream>>>(
        Bs + (size_t)c0 * DIM, bn + c0, As, an, Rb, os);
    int gy = C / 256;
    dim3 gg(32 * gy);
    int scb = (C + 255) / 256;
    for (int it = 0; it < CG_ITERS; ++it) {
      const unsigned short* Ain = (it == 0) ? Rb : Pb;
      int fin = (it == CG_ITERS - 1) ? 1 : 0;
      if (!fin) {
        gemm256<0><<<gg, 512, 0, stream>>>(Ain, Kb, Qb, gy, ty, pqf);
        if (it == 0)
          cg_step<true><<<C, 256, 0, stream>>>(Qb, Rb, Pb, ty, scal, pqf, os, ns);
        else
          cg_step<false><<<C, 256, 0, stream>>>(Qb, Rb, Pb, ty, scal, pqf, os, ns);
      } else {
        gemm256<1><<<gg, 512, 0, stream>>>(Ain, Kb, Qb, gy, ty, pqf);
        final_out<<<scb, 256, 0, stream>>>(pqf, scal, os, ns, out, c0, C);
      }
    }
  }
}

// Round 15
// 1980.876 us; speedup vs baseline: 1.9857x; 1.1311x over previous
//
#include <hip/hip_runtime.h>
#include <stdint.h>

// GP posterior via batched CG, 4 iterations. K_od bf16 (diag forced 0) + exact
// f32 diagonal dg=s+sn applied in cg_step (q_eff = q + dg*p). Matvec = 256x256x64
// 8-phase counted-vmcnt MFMA GEMM (87% dense peak). FINAL gemm epilogue = single
// p.q dot (r11-proven free); p'.p' for the final alpha precomputed in cg_step.

#define N_TRAIN 8192
#define N_TEST  4096
#define DIM     16
#define KDIM    8192
#define CG_ITERS 4
#define NT      (KDIM / 64)   // 128 K-tiles of BK=64

using f32x4  = __attribute__((ext_vector_type(4))) float;
using bf16x8 = __attribute__((ext_vector_type(8))) short;

static __device__ __forceinline__ unsigned short f2bf(float f) {
  unsigned u = __float_as_uint(f);
  u = (u + 0x7FFFu + ((u >> 16) & 1u)) >> 16;   // RNE
  return (unsigned short)u;
}
static __device__ __forceinline__ float bf2f(unsigned short h) {
  return __uint_as_float(((unsigned)h) << 16);
}

__device__ __forceinline__ void gl_lds16(const void* g, void* l) {
  __builtin_amdgcn_global_load_lds(
      (const __attribute__((address_space(1))) unsigned int*)g,
      (__attribute__((address_space(3))) unsigned int*)l, 16, 0, 0);
}

template <int N>
__device__ __forceinline__ void block_reduceN(float* v, float* sbuf) {
  #pragma unroll
  for (int off = 32; off > 0; off >>= 1)
    #pragma unroll
    for (int i = 0; i < N; ++i) v[i] += __shfl_down(v[i], off);
  int lane = threadIdx.x & 63, w = threadIdx.x >> 6;
  if (lane == 0)
    #pragma unroll
    for (int i = 0; i < N; ++i) sbuf[w * N + i] = v[i];
  __syncthreads();
  #pragma unroll
  for (int i = 0; i < N; ++i)
    v[i] = sbuf[i] + sbuf[N + i] + sbuf[2 * N + i] + sbuf[3 * N + i];
}

// ---- prep: rows scaled by 1/lengthscale + squared norms ----
__global__ void prep_kernel(const float* __restrict__ tx, const float* __restrict__ xx,
                            const float* __restrict__ ls,
                            float* __restrict__ As, float* __restrict__ an,
                            float* __restrict__ Bs, float* __restrict__ bn) {
  int i = blockIdx.x * 256 + threadIdx.x;
  if (i < N_TRAIN) {
    float s = 0.f;
    #pragma unroll
    for (int d = 0; d < DIM; ++d) {
      float v = tx[(size_t)i * DIM + d] / ls[d];
      As[(size_t)i * DIM + d] = v; s += v * v;
    }
    an[i] = s;
  } else if (i < N_TRAIN + N_TEST) {
    int j = i - N_TRAIN;
    float s = 0.f;
    #pragma unroll
    for (int d = 0; d < DIM; ++d) {
      float v = xx[(size_t)j * DIM + d] / ls[d];
      Bs[(size_t)j * DIM + d] = v; s += v * v;
    }
    bn[j] = s;
  }
}

// ---- kernel-matrix builder: 2 adjacent cols/thread (4B coalesced stores).
// DIAG0: force diagonal to ZERO (true diagonal handled exactly in f32). ----
template <bool DIAG0>
__global__ __launch_bounds__(256) void build_kernel(
    const float* __restrict__ RI, const float* __restrict__ nI,
    const float* __restrict__ RJ, const float* __restrict__ nJ,
    unsigned short* __restrict__ O1,
    const float* __restrict__ osc)
{
  __shared__ float aI[128 * DIM];
  __shared__ float sI[128];
  int t = threadIdx.x;
  int j0 = blockIdx.x * 512, i0 = blockIdx.y * 128;
  for (int e = t; e < 128 * DIM; e += 256) aI[e] = RI[(size_t)i0 * DIM + e];
  if (t < 128) sI[t] = nI[i0 + t];
  __syncthreads();

  int ja = j0 + 2 * t, jb = ja + 1;
  f32x4 aj0[4], aj1[4];
  const f32x4* RJa = (const f32x4*)(RJ + (size_t)ja * DIM);
  const f32x4* RJb = (const f32x4*)(RJ + (size_t)jb * DIM);
  #pragma unroll
  for (int q = 0; q < 4; ++q) { aj0[q] = RJa[q]; aj1[q] = RJb[q]; }
  float nja = nJ[ja], njb = nJ[jb];
  float s = osc[0];

  for (int ic = 0; ic < 128; ic += 2) {
    f32x4 rv[2][4];
    #pragma unroll
    for (int r = 0; r < 2; ++r)
      #pragma unroll
      for (int q = 0; q < 4; ++q)
        rv[r][q] = *(const f32x4*)&aI[(ic + r) * DIM + q * 4];
    #pragma unroll
    for (int r = 0; r < 2; ++r) {
      int i = ic + r;
      float d0 = 0.f, d1 = 0.f;
      #pragma unroll
      for (int q = 0; q < 4; ++q) {
        f32x4 ai = rv[r][q];
        d0 += ai[0]*aj0[q][0] + ai[1]*aj0[q][1] + ai[2]*aj0[q][2] + ai[3]*aj0[q][3];
        d1 += ai[0]*aj1[q][0] + ai[1]*aj1[q][1] + ai[2]*aj1[q][2] + ai[3]*aj1[q][3];
      }
      float d2a = fmaxf(sI[i] + nja - 2.f * d0, 0.f);
      float d2b = fmaxf(sI[i] + njb - 2.f * d1, 0.f);
      float va = s * __expf(-0.5f * d2a);
      float vb = s * __expf(-0.5f * d2b);
      if (DIAG0 && (i0 + i == ja)) va = 0.f;
      if (DIAG0 && (i0 + i == jb)) vb = 0.f;
      unsigned pack = (unsigned)f2bf(va) | ((unsigned)f2bf(vb) << 16);
      *(unsigned*)&O1[(size_t)(i0 + i) * KDIM + ja] = pack;
    }
  }
}

// ============  256x256 8-phase pipelined MFMA GEMM (counted vmcnt)  ============
// Q[M][8192] = P[M][8192] * K_od^T. 512 thr (2M x 4N waves), per-wave 128x64.
// FINAL=1: no Q store; epilogue single dot p.q_od -> pq[row] (r11-proven free).

__device__ __forceinline__ void stage_h(const char* gtile, int kbyte,
                                        char* ldsdst, int tid, int wave) {
  #pragma unroll
  for (int q = 0; q < 2; ++q) {
    int o = q * 8192 + tid * 16;
    int r = o >> 7;
    int c = (o & 127) ^ ((r & 7) << 4);
    gl_lds16(gtile + (size_t)r * (KDIM * 2) + kbyte + c,
             ldsdst + q * 8192 + wave * 1024);   // wave-uniform dest, HW adds lane*16
  }
}

template <int FINAL>
__global__ __launch_bounds__(512, 1) void gemm256(
    const unsigned short* __restrict__ A,   // p (Rb for it0, else Pb) [M][KDIM]
    const unsigned short* __restrict__ Bm,  // K_od [8192][KDIM] bf16
    unsigned short* __restrict__ Cq,        // Q [M][8192] bf16
    int gy, float* __restrict__ pq)
{
  __shared__ char Ab[2][2][16384];
  __shared__ char Bb[2][2][16384];
  const int tid = threadIdx.x, lane = tid & 63, wave = tid >> 6;
  const int wm = wave >> 2, wn = wave & 3;          // 2M x 4N
  const int nwg = gridDim.x, orig = blockIdx.x;
  const int wgid = (orig & 7) * (nwg >> 3) + (orig >> 3);   // XCD-chunked
  const int bx = wgid / gy, by = wgid % gy;
  const size_t HALF = (size_t)128 * KDIM * 2;

  const char* bA = (const char*)(A  + (size_t)(by * 256) * KDIM);
  const char* bB = (const char*)(Bm + (size_t)(bx * 256) * KDIM);

  const int ar = wm * 64 + (lane & 15);
  const int br = wn * 32 + (lane & 15);
  const int hi = (lane >> 4) * 16;
  int aoff[4][2], boff[2][2];
  #pragma unroll
  for (int mf = 0; mf < 4; ++mf)
    #pragma unroll
    for (int kk = 0; kk < 2; ++kk)
      aoff[mf][kk] = (ar + mf * 16) * 128 + ((hi + kk * 64) ^ ((ar & 7) << 4));
  #pragma unroll
  for (int nf = 0; nf < 2; ++nf)
    #pragma unroll
    for (int kk = 0; kk < 2; ++kk)
      boff[nf][kk] = (br + nf * 16) * 128 + ((hi + kk * 64) ^ ((br & 7) << 4));

  f32x4 acc[2][2][4][2] = {};
  bf16x8 aR[4][2], bR[2][2][2];

#define BAR() __builtin_amdgcn_s_barrier()
#define PRIO1 __builtin_amdgcn_s_setprio(1)
#define PRIO0 __builtin_amdgcn_s_setprio(0)
#define FENCE8() asm volatile("s_waitcnt vmcnt(8)" ::: "memory")
#define FENCE6() asm volatile("s_waitcnt vmcnt(6)" ::: "memory")
#define FENCE0() asm volatile("s_waitcnt vmcnt(0)" ::: "memory")
#define STAGE_A(buf, mh, kb) stage_h(bA + ((mh) ? HALF : 0), kb, &Ab[buf][mh][0], tid, wave)
#define STAGE_B(buf, mh, kb) stage_h(bB + ((mh) ? HALF : 0), kb, &Bb[buf][mh][0], tid, wave)
#define LOAD_A(buf, mh)                                                        \
  { _Pragma("unroll") for (int mf = 0; mf < 4; ++mf)                           \
      _Pragma("unroll") for (int kk = 0; kk < 2; ++kk)                         \
        aR[mf][kk] = *(const bf16x8*)(&Ab[buf][mh][0] + aoff[mf][kk]); }
#define LOAD_B(buf, nh)                                                        \
  { _Pragma("unroll") for (int nf = 0; nf < 2; ++nf)                           \
      _Pragma("unroll") for (int kk = 0; kk < 2; ++kk)                         \
        bR[nh][nf][kk] = *(const bf16x8*)(&Bb[buf][nh][0] + boff[nf][kk]); }
#define MFMA16(mh, nh)                                                         \
  { _Pragma("unroll") for (int kk = 0; kk < 2; ++kk)                           \
      _Pragma("unroll") for (int mf = 0; mf < 4; ++mf)                         \
        _Pragma("unroll") for (int nf = 0; nf < 2; ++nf)                       \
          acc[mh][nh][mf][nf] = __builtin_amdgcn_mfma_f32_16x16x32_bf16(       \
              aR[mf][kk], bR[nh][nf][kk], acc[mh][nh][mf][nf], 0, 0, 0); }

  STAGE_A(0, 0, 0);   STAGE_B(0, 0, 0);   STAGE_B(0, 1, 0);   STAGE_A(0, 1, 0);
  STAGE_A(1, 0, 128); STAGE_B(1, 0, 128); STAGE_B(1, 1, 128); STAGE_A(1, 1, 128);
  FENCE6();
  BAR();

  for (int t = 0; t < NT; t += 2) {
    const bool g = (t + 2 < NT);
    const int kb2 = (t + 2) * 128, kb3 = (t + 3) * 128;
    LOAD_A(0, 0); LOAD_B(0, 0);
    BAR(); PRIO1; MFMA16(0, 0); PRIO0; BAR();
    if (g) STAGE_A(0, 0, kb2);
    LOAD_B(0, 1);
    BAR(); PRIO1; MFMA16(0, 1); PRIO0; BAR();
    if (g) STAGE_B(0, 0, kb2);
    LOAD_A(0, 1);
    BAR(); PRIO1; MFMA16(1, 0); PRIO0; BAR();
    if (g) { STAGE_B(0, 1, kb2); STAGE_A(0, 1, kb2); }
    BAR(); PRIO1; MFMA16(1, 1); PRIO0;
    if (g) { FENCE8(); } else { FENCE0(); }
    BAR();
    LOAD_A(1, 0); LOAD_B(1, 0);
    BAR(); PRIO1; MFMA16(0, 0); PRIO0; BAR();
    if (g) STAGE_A(1, 0, kb3);
    LOAD_B(1, 1);
    BAR(); PRIO1; MFMA16(0, 1); PRIO0; BAR();
    if (g) STAGE_B(1, 0, kb3);
    LOAD_A(1, 1);
    BAR(); PRIO1; MFMA16(1, 0); PRIO0; BAR();
    if (g) { STAGE_B(1, 1, kb3); STAGE_A(1, 1, kb3); }
    BAR(); PRIO1; MFMA16(1, 1); PRIO0;
    if (g) { FENCE6(); }
    BAR();
  }

  const int bm = by * 256, bn = bx * 256;
  if (!FINAL) {
    // C/D mapping (verified): col = lane&15, row = (lane>>4)*4 + reg
    #pragma unroll
    for (int mh = 0; mh < 2; ++mh)
      #pragma unroll
      for (int nh = 0; nh < 2; ++nh)
        #pragma unroll
        for (int mf = 0; mf < 4; ++mf)
          #pragma unroll
          for (int nf = 0; nf < 2; ++nf) {
            int row = bm + mh * 128 + wm * 64 + mf * 16 + (lane >> 4) * 4;
            int col = bn + nh * 128 + wn * 32 + nf * 16 + (lane & 15);
            #pragma unroll
            for (int rg = 0; rg < 4; ++rg)
              Cq[(size_t)(row + rg) * KDIM + col] = f2bf(acc[mh][nh][mf][nf][rg]);
          }
  } else {
    // final iteration: single dot. pq[row] += sum_col P[row][col]*Q_od[row][col]
    #pragma unroll
    for (int mh = 0; mh < 2; ++mh)
      #pragma unroll
      for (int mf = 0; mf < 4; ++mf)
        #pragma unroll
        for (int rg = 0; rg < 4; ++rg) {
          int row = bm + mh * 128 + wm * 64 + mf * 16 + (lane >> 4) * 4 + rg;
          float v = 0.f;
          #pragma unroll
          for (int nh = 0; nh < 2; ++nh)
            #pragma unroll
            for (int nf = 0; nf < 2; ++nf) {
              int col = bn + nh * 128 + wn * 32 + nf * 16 + (lane & 15);
              v += acc[mh][nh][mf][nf][rg] * bf2f(A[(size_t)row * KDIM + col]);
            }
          v += __shfl_xor(v, 1); v += __shfl_xor(v, 2);
          v += __shfl_xor(v, 4); v += __shfl_xor(v, 8);
          if ((lane & 15) == 0) atomicAdd(&pq[row], v);
        }
  }
#undef MFMA16
#undef LOAD_B
#undef LOAD_A
#undef STAGE_B
#undef STAGE_A
#undef FENCE0
#undef FENCE6
#undef FENCE8
#undef PRIO0
#undef PRIO1
#undef BAR
}

// ---- CG step with exact-diagonal correction: q_eff = q_od + dg*p.
// scal[c*8]: {rr, yp, yr, mean, bx, pp'}. One main reduce + one small pp' reduce. ----
template <bool FIRST>
__global__ __launch_bounds__(256) void cg_step(
    const unsigned short* __restrict__ Q, unsigned short* __restrict__ R,
    unsigned short* __restrict__ P, const float* __restrict__ y,
    float* __restrict__ scal, float* __restrict__ pq,
    const float* __restrict__ osc, const float* __restrict__ noi)
{
  __shared__ float sbuf[24];
  int c = blockIdx.x, t = threadIdx.x;
  size_t base = (size_t)c * KDIM;
  float dg = osc[0] + noi[0];       // exact f32 diagonal of Khat

  bf16x8 q8[4], r8[4], p8[4];
  #pragma unroll
  for (int k = 0; k < 4; ++k) q8[k] = *(const bf16x8*)&Q[base + k * 2048 + t * 8];
  #pragma unroll
  for (int k = 0; k < 4; ++k) r8[k] = *(const bf16x8*)&R[base + k * 2048 + t * 8];
  if (FIRST) {
    #pragma unroll
    for (int k = 0; k < 4; ++k) p8[k] = r8[k];
  } else {
    #pragma unroll
    for (int k = 0; k < 4; ++k) p8[k] = *(const bf16x8*)&P[base + k * 2048 + t * 8];
  }

  // FIRST: v = {p.q, q.q, y.q, r.r, y.r, -}; MID: v = {p.q, r.q, q.q, y.q, p.p, r.p}
  float v[6] = {0.f, 0.f, 0.f, 0.f, 0.f, 0.f};
  #pragma unroll
  for (int k = 0; k < 4; ++k) {
    int j = k * 2048 + t * 8;
    f32x4 ya = *(const f32x4*)&y[j];
    f32x4 yb = *(const f32x4*)&y[j + 4];
    #pragma unroll
    for (int e = 0; e < 8; ++e) {
      float qv = bf2f((unsigned short)q8[k][e]);
      float rv = bf2f((unsigned short)r8[k][e]);
      float yv = (e < 4) ? ya[e] : yb[e - 4];
      if (FIRST) {
        v[0] += rv * qv; v[1] += qv * qv; v[2] += yv * qv;
        v[3] += rv * rv; v[4] += yv * rv;
      } else {
        float pv = bf2f((unsigned short)p8[k][e]);
        v[0] += pv * qv; v[1] += rv * qv; v[2] += qv * qv; v[3] += yv * qv;
        v[4] += pv * pv; v[5] += rv * pv;
      }
    }
  }
  block_reduceN<6>(v, sbuf);

  float rr, yp, yr, mean, bx;
  float pq_od, rq_od, qq_od, yq_od, pp, rp;
  if (FIRST) {
    rr = v[3]; yp = v[4]; yr = v[4]; mean = 0.f; bx = 0.f;
    pq_od = v[0]; rq_od = v[0]; qq_od = v[1]; yq_od = v[2];
    pp = v[3]; rp = v[3];
  } else {
    rr = scal[c*8+0]; yp = scal[c*8+1]; yr = scal[c*8+2];
    mean = scal[c*8+3]; bx = scal[c*8+4];
    pq_od = v[0]; rq_od = v[1]; qq_od = v[2]; yq_od = v[3];
    pp = v[4]; rp = v[5];
  }
  float pAp   = pq_od + dg * pp;
  float rq_e  = rq_od + dg * rp;
  float qq_e  = qq_od + 2.f * dg * pq_od + dg * dg * pp;
  float yq_e  = yq_od + dg * yp;

  float alpha = rr / fmaxf(pAp, 1e-30f);
  mean += alpha * yp;
  bx   += alpha * rr;
  float rrn = fmaxf(rr - 2.f * alpha * rq_e + alpha * alpha * qq_e, 0.f);
  float yrn = yr - alpha * yq_e;
  float beta = rrn / fmaxf(rr, 1e-30f);
  float ypn  = yrn + beta * yp;

  // fused update: r' = r - alpha*(q + dg*p); p' = r'(rounded) + beta*p
  // also accumulate pp' = sum p'^2 (over the ROUNDED stored values)
  float spp = 0.f;
  #pragma unroll
  for (int k = 0; k < 4; ++k) {
    int j = k * 2048 + t * 8;
    bf16x8 wr, wp;
    #pragma unroll
    for (int e = 0; e < 8; ++e) {
      float pv = bf2f((unsigned short)p8[k][e]);
      float qe = bf2f((unsigned short)q8[k][e]) + dg * pv;
      float rn = bf2f((unsigned short)r8[k][e]) - alpha * qe;
      unsigned short hb = f2bf(rn);
      wr[e] = (short)hb;
      unsigned short hp = f2bf(bf2f(hb) + beta * pv);
      wp[e] = (short)hp;
      float ppv = bf2f(hp);
      spp += ppv * ppv;
    }
    *(bf16x8*)&R[base + j] = wr;
    *(bf16x8*)&P[base + j] = wp;
  }
  __syncthreads();                 // sbuf safe to reuse
  float vv[1] = {spp};
  block_reduceN<1>(vv, sbuf);

  if (t == 0) {
    scal[c*8+0] = rrn; scal[c*8+1] = ypn; scal[c*8+2] = yrn;
    scal[c*8+3] = mean; scal[c*8+4] = bx; scal[c*8+5] = vv[0];
    pq[c] = 0.f;   // zero for the FINAL gemm's atomics
  }
}

// ---- final outputs: last alpha from pq (p.q_od) + precomputed pp' ----
__global__ void final_out(float* __restrict__ pq, const float* __restrict__ scal,
                          const float* __restrict__ osc, const float* __restrict__ noi,
                          float* __restrict__ out, int c0, int C)
{
  int c = blockIdx.x * 256 + threadIdx.x;
  if (c >= C) return;
  float dg = osc[0] + noi[0];
  float rr = scal[c*8+0], yp = scal[c*8+1];
  float mean = scal[c*8+3], bx = scal[c*8+4], pp = scal[c*8+5];
  float pAp = pq[c] + dg * pp;
  float alpha = rr / fmaxf(pAp, 1e-30f);
  mean += alpha * yp;
  bx   += alpha * rr;
  out[c0 + c] = mean;
  out[N_TEST + c0 + c] = dg - bx;    // s + sn - b.x
  pq[c] = 0.f;
}

extern "C" void kernel_launch(void* const* d_in, const int* in_sizes, int n_in,
                              void* d_out, int out_size, void* d_ws, size_t ws_size,
                              hipStream_t stream) {
  const float* tx = (const float*)d_in[0];
  const float* ty = (const float*)d_in[1];
  const float* xx = (const float*)d_in[2];
  const float* os = (const float*)d_in[3];
  const float* ls = (const float*)d_in[4];
  const float* ns = (const float*)d_in[5];
  float* out = (float*)d_out;
  (void)in_sizes; (void)n_in; (void)out_size;

  auto pad = [](size_t x) { return (x + 255) & ~(size_t)255; };
  size_t fixed = pad((size_t)N_TRAIN * KDIM * 2)
               + pad((size_t)N_TRAIN * DIM * 4) + pad((size_t)N_TRAIN * 4)
               + pad((size_t)N_TEST * DIM * 4) + pad((size_t)N_TEST * 4);
  int C = 4096;
  while (C > 256) {
    size_t tot = fixed + 3 * pad((size_t)C * KDIM * 2)
               + pad((size_t)C * 32) + pad((size_t)C * 4);
    if (tot <= ws_size) break;
    C >>= 1;
  }

  char* w = (char*)d_ws;
  auto alloc = [&](size_t bytes) { char* p = w; w += ((bytes + 255) & ~(size_t)255); return p; };
  unsigned short* Kb = (unsigned short*)alloc((size_t)N_TRAIN * KDIM * 2);
  float* As = (float*)alloc((size_t)N_TRAIN * DIM * 4);
  float* an = (float*)alloc((size_t)N_TRAIN * 4);
  float* Bs = (float*)alloc((size_t)N_TEST * DIM * 4);
  float* bn = (float*)alloc((size_t)N_TEST * 4);
  unsigned short* Rb = (unsigned short*)alloc((size_t)C * KDIM * 2);
  unsigned short* Pb = (unsigned short*)alloc((size_t)C * KDIM * 2);
  unsigned short* Qb = (unsigned short*)alloc((size_t)C * KDIM * 2);
  float* scal = (float*)alloc((size_t)C * 32);
  float* pq   = (float*)alloc((size_t)C * 4);

  prep_kernel<<<48, 256, 0, stream>>>(tx, xx, ls, As, an, Bs, bn);

  build_kernel<true><<<dim3(KDIM / 512, N_TRAIN / 128), 256, 0, stream>>>(
      As, an, As, an, Kb, os);

  for (int c0 = 0; c0 < N_TEST; c0 += C) {
    build_kernel<false><<<dim3(KDIM / 512, C / 128), 256, 0, stream>>>(
        Bs + (size_t)c0 * DIM, bn + c0, As, an, Rb, os);
    int gy = C / 256;
    dim3 gg(32 * gy);
    int scb = (C + 255) / 256;
    for (int it = 0; it < CG_ITERS; ++it) {
      const unsigned short* Ain = (it == 0) ? Rb : Pb;
      int fin = (it == CG_ITERS - 1) ? 1 : 0;
      if (!fin) {
        gemm256<0><<<gg, 512, 0, stream>>>(Ain, Kb, Qb, gy, pq);
        if (it == 0)
          cg_step<true><<<C, 256, 0, stream>>>(Qb, Rb, Pb, ty, scal, pq, os, ns);
        else
          cg_step<false><<<C, 256, 0, stream>>>(Qb, Rb, Pb, ty, scal, pq, os, ns);
      } else {
        gemm256<1><<<gg, 512, 0, stream>>>(Ain, Kb, Qb, gy, pq);
        final_out<<<scb, 256, 0, stream>>>(pq, scal, os, ns, out, c0, C);
      }
    }
  }
}

// Round 16
// 1929.687 us; speedup vs baseline: 2.0383x; 1.0265x over previous
//
#include <hip/hip_runtime.h>
#include <stdint.h>

// GP posterior via batched CG, 4 iterations. K_od bf16 (diag 0) + exact f32
// diagonal dg=s+sn in cg_step. Matvec = 256x256x64 8-phase counted-vmcnt MFMA
// GEMM (87% dense peak). NEW r16: kernel-matrix builds via MFMA with split-bf16
// coordinates (a = hi + lo; dot = mfma([hi|lo],[bhi|bhi]) + mfma([hi|lo],[blo|blo])).

#define N_TRAIN 8192
#define N_TEST  4096
#define DIM     16
#define KDIM    8192
#define CG_ITERS 4
#define NT      (KDIM / 64)   // 128 K-tiles of BK=64

using f32x4  = __attribute__((ext_vector_type(4))) float;
using bf16x8 = __attribute__((ext_vector_type(8))) short;

static __device__ __forceinline__ unsigned short f2bf(float f) {
  unsigned u = __float_as_uint(f);
  u = (u + 0x7FFFu + ((u >> 16) & 1u)) >> 16;   // RNE
  return (unsigned short)u;
}
static __device__ __forceinline__ float bf2f(unsigned short h) {
  return __uint_as_float(((unsigned)h) << 16);
}

__device__ __forceinline__ void gl_lds16(const void* g, void* l) {
  __builtin_amdgcn_global_load_lds(
      (const __attribute__((address_space(1))) unsigned int*)g,
      (__attribute__((address_space(3))) unsigned int*)l, 16, 0, 0);
}

template <int N>
__device__ __forceinline__ void block_reduceN(float* v, float* sbuf) {
  #pragma unroll
  for (int off = 32; off > 0; off >>= 1)
    #pragma unroll
    for (int i = 0; i < N; ++i) v[i] += __shfl_down(v[i], off);
  int lane = threadIdx.x & 63, w = threadIdx.x >> 6;
  if (lane == 0)
    #pragma unroll
    for (int i = 0; i < N; ++i) sbuf[w * N + i] = v[i];
  __syncthreads();
  #pragma unroll
  for (int i = 0; i < N; ++i)
    v[i] = sbuf[i] + sbuf[N + i] + sbuf[2 * N + i] + sbuf[3 * N + i];
}

// ---- prep: split-bf16 packs + squared norms ----
// train i: TPK[i][32]={hi,lo}, THH[i][32]={hi,hi}, TLL[i][32]={lo,lo}, an[i]
// test  j: XPK[j][32]={hi,lo}, bn[j]
__global__ void prep_kernel(const float* __restrict__ tx, const float* __restrict__ xx,
                            const float* __restrict__ ls,
                            unsigned short* __restrict__ TPK,
                            unsigned short* __restrict__ THH,
                            unsigned short* __restrict__ TLL,
                            float* __restrict__ an,
                            unsigned short* __restrict__ XPK,
                            float* __restrict__ bn) {
  int i = blockIdx.x * 256 + threadIdx.x;
  if (i < N_TRAIN) {
    float s = 0.f;
    #pragma unroll
    for (int d = 0; d < DIM; ++d) {
      float v = tx[(size_t)i * DIM + d] / ls[d];
      s += v * v;
      unsigned short hi = f2bf(v);
      unsigned short lo = f2bf(v - bf2f(hi));
      TPK[(size_t)i * 32 + d] = hi;  TPK[(size_t)i * 32 + 16 + d] = lo;
      THH[(size_t)i * 32 + d] = hi;  THH[(size_t)i * 32 + 16 + d] = hi;
      TLL[(size_t)i * 32 + d] = lo;  TLL[(size_t)i * 32 + 16 + d] = lo;
    }
    an[i] = s;
  } else if (i < N_TRAIN + N_TEST) {
    int j = i - N_TRAIN;
    float s = 0.f;
    #pragma unroll
    for (int d = 0; d < DIM; ++d) {
      float v = xx[(size_t)j * DIM + d] / ls[d];
      s += v * v;
      unsigned short hi = f2bf(v);
      unsigned short lo = f2bf(v - bf2f(hi));
      XPK[(size_t)j * 32 + d] = hi;  XPK[(size_t)j * 32 + 16 + d] = lo;
    }
    bn[j] = s;
  }
}

// ---- MFMA kernel-matrix builder: 128x128 tile per block, 4 waves (32-row strips).
// dot[i][j] via 2x mfma_f32_16x16x32_bf16; epilogue exp in f32; LDS-staged
// coalesced output. DIAG0: force diagonal (global i==j) to zero. ----
#define TLDS 136   // padded LDS row stride (bf16 elems): 272B, 16B-aligned, bank-spread

template <bool DIAG0>
__global__ __launch_bounds__(256) void build_mfma(
    const unsigned short* __restrict__ IPK,  // [NI][32] {hi|lo} row side
    const float* __restrict__ nI,
    const unsigned short* __restrict__ JHH,  // [8192][32] {hi|hi} col side (train)
    const unsigned short* __restrict__ JLL,  // [8192][32] {lo|lo}
    const float* __restrict__ nJ,
    unsigned short* __restrict__ O,          // [NI][KDIM] bf16
    const float* __restrict__ osc)
{
  __shared__ unsigned short tile[128 * TLDS];
  __shared__ float sI[128], sJ[128];
  int t = threadIdx.x, lane = t & 63, wave = t >> 6;
  int i0 = blockIdx.y * 128, j0 = blockIdx.x * 128;
  if (t < 128) sI[t] = nI[i0 + t];
  else         sJ[t - 128] = nJ[j0 + t - 128];
  __syncthreads();

  float s = osc[0];
  int ir = lane & 15, ks = lane >> 4;      // frag index / k-slice

  // A-frags: two 16-row tiles of this wave's 32-row strip
  bf16x8 af[2];
  #pragma unroll
  for (int rt = 0; rt < 2; ++rt)
    af[rt] = *(const bf16x8*)&IPK[(size_t)(i0 + (wave * 2 + rt) * 16 + ir) * 32 + ks * 8];

  for (int jt = 0; jt < 8; ++jt) {
    bf16x8 bh = *(const bf16x8*)&JHH[(size_t)(j0 + jt * 16 + ir) * 32 + ks * 8];
    bf16x8 bl = *(const bf16x8*)&JLL[(size_t)(j0 + jt * 16 + ir) * 32 + ks * 8];
    f32x4 acc0 = {}, acc1 = {};
    acc0 = __builtin_amdgcn_mfma_f32_16x16x32_bf16(af[0], bh, acc0, 0, 0, 0);
    acc0 = __builtin_amdgcn_mfma_f32_16x16x32_bf16(af[0], bl, acc0, 0, 0, 0);
    acc1 = __builtin_amdgcn_mfma_f32_16x16x32_bf16(af[1], bh, acc1, 0, 0, 0);
    acc1 = __builtin_amdgcn_mfma_f32_16x16x32_bf16(af[1], bl, acc1, 0, 0, 0);
    // epilogue (verified C/D mapping: col = lane&15, row = (lane>>4)*4 + rg)
    #pragma unroll
    for (int rt = 0; rt < 2; ++rt) {
      f32x4 a = rt ? acc1 : acc0;
      #pragma unroll
      for (int rg = 0; rg < 4; ++rg) {
        int lrow = (wave * 2 + rt) * 16 + ks * 4 + rg;
        int lcol = jt * 16 + ir;
        float d2 = fmaxf(sI[lrow] + sJ[lcol] - 2.f * a[rg], 0.f);
        float v = s * __expf(-0.5f * d2);
        if (DIAG0 && (i0 + lrow == j0 + lcol)) v = 0.f;
        tile[lrow * TLDS + lcol] = f2bf(v);
      }
    }
  }
  __syncthreads();
  // coalesced flush: 8 passes x (16 rows x 128 cols)
  #pragma unroll
  for (int pass = 0; pass < 8; ++pass) {
    int r = pass * 16 + (t >> 4);
    int cb = (t & 15) * 8;
    *(bf16x8*)&O[(size_t)(i0 + r) * KDIM + j0 + cb] =
        *(const bf16x8*)&tile[r * TLDS + cb];
  }
}

// ============  256x256 8-phase pipelined MFMA GEMM (counted vmcnt)  ============
__device__ __forceinline__ void stage_h(const char* gtile, int kbyte,
                                        char* ldsdst, int tid, int wave) {
  #pragma unroll
  for (int q = 0; q < 2; ++q) {
    int o = q * 8192 + tid * 16;
    int r = o >> 7;
    int c = (o & 127) ^ ((r & 7) << 4);
    gl_lds16(gtile + (size_t)r * (KDIM * 2) + kbyte + c,
             ldsdst + q * 8192 + wave * 1024);   // wave-uniform dest, HW adds lane*16
  }
}

template <int FINAL>
__global__ __launch_bounds__(512, 1) void gemm256(
    const unsigned short* __restrict__ A,   // p (Rb for it0, else Pb) [M][KDIM]
    const unsigned short* __restrict__ Bm,  // K_od [8192][KDIM] bf16
    unsigned short* __restrict__ Cq,        // Q [M][8192] bf16
    int gy, float* __restrict__ pq)
{
  __shared__ char Ab[2][2][16384];
  __shared__ char Bb[2][2][16384];
  const int tid = threadIdx.x, lane = tid & 63, wave = tid >> 6;
  const int wm = wave >> 2, wn = wave & 3;          // 2M x 4N
  const int nwg = gridDim.x, orig = blockIdx.x;
  const int wgid = (orig & 7) * (nwg >> 3) + (orig >> 3);   // XCD-chunked
  const int bx = wgid / gy, by = wgid % gy;
  const size_t HALF = (size_t)128 * KDIM * 2;

  const char* bA = (const char*)(A  + (size_t)(by * 256) * KDIM);
  const char* bB = (const char*)(Bm + (size_t)(bx * 256) * KDIM);

  const int ar = wm * 64 + (lane & 15);
  const int br = wn * 32 + (lane & 15);
  const int hi = (lane >> 4) * 16;
  int aoff[4][2], boff[2][2];
  #pragma unroll
  for (int mf = 0; mf < 4; ++mf)
    #pragma unroll
    for (int kk = 0; kk < 2; ++kk)
      aoff[mf][kk] = (ar + mf * 16) * 128 + ((hi + kk * 64) ^ ((ar & 7) << 4));
  #pragma unroll
  for (int nf = 0; nf < 2; ++nf)
    #pragma unroll
    for (int kk = 0; kk < 2; ++kk)
      boff[nf][kk] = (br + nf * 16) * 128 + ((hi + kk * 64) ^ ((br & 7) << 4));

  f32x4 acc[2][2][4][2] = {};
  bf16x8 aR[4][2], bR[2][2][2];

#define BAR() __builtin_amdgcn_s_barrier()
#define PRIO1 __builtin_amdgcn_s_setprio(1)
#define PRIO0 __builtin_amdgcn_s_setprio(0)
#define FENCE8() asm volatile("s_waitcnt vmcnt(8)" ::: "memory")
#define FENCE6() asm volatile("s_waitcnt vmcnt(6)" ::: "memory")
#define FENCE0() asm volatile("s_waitcnt vmcnt(0)" ::: "memory")
#define STAGE_A(buf, mh, kb) stage_h(bA + ((mh) ? HALF : 0), kb, &Ab[buf][mh][0], tid, wave)
#define STAGE_B(buf, mh, kb) stage_h(bB + ((mh) ? HALF : 0), kb, &Bb[buf][mh][0], tid, wave)
#define LOAD_A(buf, mh)                                                        \
  { _Pragma("unroll") for (int mf = 0; mf < 4; ++mf)                           \
      _Pragma("unroll") for (int kk = 0; kk < 2; ++kk)                         \
        aR[mf][kk] = *(const bf16x8*)(&Ab[buf][mh][0] + aoff[mf][kk]); }
#define LOAD_B(buf, nh)                                                        \
  { _Pragma("unroll") for (int nf = 0; nf < 2; ++nf)                           \
      _Pragma("unroll") for (int kk = 0; kk < 2; ++kk)                         \
        bR[nh][nf][kk] = *(const bf16x8*)(&Bb[buf][nh][0] + boff[nf][kk]); }
#define MFMA16(mh, nh)                                                         \
  { _Pragma("unroll") for (int kk = 0; kk < 2; ++kk)                           \
      _Pragma("unroll") for (int mf = 0; mf < 4; ++mf)                         \
        _Pragma("unroll") for (int nf = 0; nf < 2; ++nf)                       \
          acc[mh][nh][mf][nf] = __builtin_amdgcn_mfma_f32_16x16x32_bf16(       \
              aR[mf][kk], bR[nh][nf][kk], acc[mh][nh][mf][nf], 0, 0, 0); }

  STAGE_A(0, 0, 0);   STAGE_B(0, 0, 0);   STAGE_B(0, 1, 0);   STAGE_A(0, 1, 0);
  STAGE_A(1, 0, 128); STAGE_B(1, 0, 128); STAGE_B(1, 1, 128); STAGE_A(1, 1, 128);
  FENCE6();
  BAR();

  for (int t = 0; t < NT; t += 2) {
    const bool g = (t + 2 < NT);
    const int kb2 = (t + 2) * 128, kb3 = (t + 3) * 128;
    LOAD_A(0, 0); LOAD_B(0, 0);
    BAR(); PRIO1; MFMA16(0, 0); PRIO0; BAR();
    if (g) STAGE_A(0, 0, kb2);
    LOAD_B(0, 1);
    BAR(); PRIO1; MFMA16(0, 1); PRIO0; BAR();
    if (g) STAGE_B(0, 0, kb2);
    LOAD_A(0, 1);
    BAR(); PRIO1; MFMA16(1, 0); PRIO0; BAR();
    if (g) { STAGE_B(0, 1, kb2); STAGE_A(0, 1, kb2); }
    BAR(); PRIO1; MFMA16(1, 1); PRIO0;
    if (g) { FENCE8(); } else { FENCE0(); }
    BAR();
    LOAD_A(1, 0); LOAD_B(1, 0);
    BAR(); PRIO1; MFMA16(0, 0); PRIO0; BAR();
    if (g) STAGE_A(1, 0, kb3);
    LOAD_B(1, 1);
    BAR(); PRIO1; MFMA16(0, 1); PRIO0; BAR();
    if (g) STAGE_B(1, 0, kb3);
    LOAD_A(1, 1);
    BAR(); PRIO1; MFMA16(1, 0); PRIO0; BAR();
    if (g) { STAGE_B(1, 1, kb3); STAGE_A(1, 1, kb3); }
    BAR(); PRIO1; MFMA16(1, 1); PRIO0;
    if (g) { FENCE6(); }
    BAR();
  }

  const int bm = by * 256, bn = bx * 256;
  if (!FINAL) {
    // C/D mapping (verified): col = lane&15, row = (lane>>4)*4 + reg
    #pragma unroll
    for (int mh = 0; mh < 2; ++mh)
      #pragma unroll
      for (int nh = 0; nh < 2; ++nh)
        #pragma unroll
        for (int mf = 0; mf < 4; ++mf)
          #pragma unroll
          for (int nf = 0; nf < 2; ++nf) {
            int row = bm + mh * 128 + wm * 64 + mf * 16 + (lane >> 4) * 4;
            int col = bn + nh * 128 + wn * 32 + nf * 16 + (lane & 15);
            #pragma unroll
            for (int rg = 0; rg < 4; ++rg)
              Cq[(size_t)(row + rg) * KDIM + col] = f2bf(acc[mh][nh][mf][nf][rg]);
          }
  } else {
    // final iteration: single dot. pq[row] += sum_col P[row][col]*Q_od[row][col]
    #pragma unroll
    for (int mh = 0; mh < 2; ++mh)
      #pragma unroll
      for (int mf = 0; mf < 4; ++mf)
        #pragma unroll
        for (int rg = 0; rg < 4; ++rg) {
          int row = bm + mh * 128 + wm * 64 + mf * 16 + (lane >> 4) * 4 + rg;
          float v = 0.f;
          #pragma unroll
          for (int nh = 0; nh < 2; ++nh)
            #pragma unroll
            for (int nf = 0; nf < 2; ++nf) {
              int col = bn + nh * 128 + wn * 32 + nf * 16 + (lane & 15);
              v += acc[mh][nh][mf][nf][rg] * bf2f(A[(size_t)row * KDIM + col]);
            }
          v += __shfl_xor(v, 1); v += __shfl_xor(v, 2);
          v += __shfl_xor(v, 4); v += __shfl_xor(v, 8);
          if ((lane & 15) == 0) atomicAdd(&pq[row], v);
        }
  }
#undef MFMA16
#undef LOAD_B
#undef LOAD_A
#undef STAGE_B
#undef STAGE_A
#undef FENCE0
#undef FENCE6
#undef FENCE8
#undef PRIO0
#undef PRIO1
#undef BAR
}

// ---- CG step with exact-diagonal correction (unchanged from r15) ----
template <bool FIRST>
__global__ __launch_bounds__(256) void cg_step(
    const unsigned short* __restrict__ Q, unsigned short* __restrict__ R,
    unsigned short* __restrict__ P, const float* __restrict__ y,
    float* __restrict__ scal, float* __restrict__ pq,
    const float* __restrict__ osc, const float* __restrict__ noi)
{
  __shared__ float sbuf[24];
  int c = blockIdx.x, t = threadIdx.x;
  size_t base = (size_t)c * KDIM;
  float dg = osc[0] + noi[0];       // exact f32 diagonal of Khat

  bf16x8 q8[4], r8[4], p8[4];
  #pragma unroll
  for (int k = 0; k < 4; ++k) q8[k] = *(const bf16x8*)&Q[base + k * 2048 + t * 8];
  #pragma unroll
  for (int k = 0; k < 4; ++k) r8[k] = *(const bf16x8*)&R[base + k * 2048 + t * 8];
  if (FIRST) {
    #pragma unroll
    for (int k = 0; k < 4; ++k) p8[k] = r8[k];
  } else {
    #pragma unroll
    for (int k = 0; k < 4; ++k) p8[k] = *(const bf16x8*)&P[base + k * 2048 + t * 8];
  }

  float v[6] = {0.f, 0.f, 0.f, 0.f, 0.f, 0.f};
  #pragma unroll
  for (int k = 0; k < 4; ++k) {
    int j = k * 2048 + t * 8;
    f32x4 ya = *(const f32x4*)&y[j];
    f32x4 yb = *(const f32x4*)&y[j + 4];
    #pragma unroll
    for (int e = 0; e < 8; ++e) {
      float qv = bf2f((unsigned short)q8[k][e]);
      float rv = bf2f((unsigned short)r8[k][e]);
      float yv = (e < 4) ? ya[e] : yb[e - 4];
      if (FIRST) {
        v[0] += rv * qv; v[1] += qv * qv; v[2] += yv * qv;
        v[3] += rv * rv; v[4] += yv * rv;
      } else {
        float pv = bf2f((unsigned short)p8[k][e]);
        v[0] += pv * qv; v[1] += rv * qv; v[2] += qv * qv; v[3] += yv * qv;
        v[4] += pv * pv; v[5] += rv * pv;
      }
    }
  }
  block_reduceN<6>(v, sbuf);

  float rr, yp, yr, mean, bx;
  float pq_od, rq_od, qq_od, yq_od, pp, rp;
  if (FIRST) {
    rr = v[3]; yp = v[4]; yr = v[4]; mean = 0.f; bx = 0.f;
    pq_od = v[0]; rq_od = v[0]; qq_od = v[1]; yq_od = v[2];
    pp = v[3]; rp = v[3];
  } else {
    rr = scal[c*8+0]; yp = scal[c*8+1]; yr = scal[c*8+2];
    mean = scal[c*8+3]; bx = scal[c*8+4];
    pq_od = v[0]; rq_od = v[1]; qq_od = v[2]; yq_od = v[3];
    pp = v[4]; rp = v[5];
  }
  float pAp   = pq_od + dg * pp;
  float rq_e  = rq_od + dg * rp;
  float qq_e  = qq_od + 2.f * dg * pq_od + dg * dg * pp;
  float yq_e  = yq_od + dg * yp;

  float alpha = rr / fmaxf(pAp, 1e-30f);
  mean += alpha * yp;
  bx   += alpha * rr;
  float rrn = fmaxf(rr - 2.f * alpha * rq_e + alpha * alpha * qq_e, 0.f);
  float yrn = yr - alpha * yq_e;
  float beta = rrn / fmaxf(rr, 1e-30f);
  float ypn  = yrn + beta * yp;

  float spp = 0.f;
  #pragma unroll
  for (int k = 0; k < 4; ++k) {
    int j = k * 2048 + t * 8;
    bf16x8 wr, wp;
    #pragma unroll
    for (int e = 0; e < 8; ++e) {
      float pv = bf2f((unsigned short)p8[k][e]);
      float qe = bf2f((unsigned short)q8[k][e]) + dg * pv;
      float rn = bf2f((unsigned short)r8[k][e]) - alpha * qe;
      unsigned short hb = f2bf(rn);
      wr[e] = (short)hb;
      unsigned short hp = f2bf(bf2f(hb) + beta * pv);
      wp[e] = (short)hp;
      float ppv = bf2f(hp);
      spp += ppv * ppv;
    }
    *(bf16x8*)&R[base + j] = wr;
    *(bf16x8*)&P[base + j] = wp;
  }
  __syncthreads();
  float vv[1] = {spp};
  block_reduceN<1>(vv, sbuf);

  if (t == 0) {
    scal[c*8+0] = rrn; scal[c*8+1] = ypn; scal[c*8+2] = yrn;
    scal[c*8+3] = mean; scal[c*8+4] = bx; scal[c*8+5] = vv[0];
    pq[c] = 0.f;
  }
}

// ---- final outputs ----
__global__ void final_out(float* __restrict__ pq, const float* __restrict__ scal,
                          const float* __restrict__ osc, const float* __restrict__ noi,
                          float* __restrict__ out, int c0, int C)
{
  int c = blockIdx.x * 256 + threadIdx.x;
  if (c >= C) return;
  float dg = osc[0] + noi[0];
  float rr = scal[c*8+0], yp = scal[c*8+1];
  float mean = scal[c*8+3], bx = scal[c*8+4], pp = scal[c*8+5];
  float pAp = pq[c] + dg * pp;
  float alpha = rr / fmaxf(pAp, 1e-30f);
  mean += alpha * yp;
  bx   += alpha * rr;
  out[c0 + c] = mean;
  out[N_TEST + c0 + c] = dg - bx;
  pq[c] = 0.f;
}

extern "C" void kernel_launch(void* const* d_in, const int* in_sizes, int n_in,
                              void* d_out, int out_size, void* d_ws, size_t ws_size,
                              hipStream_t stream) {
  const float* tx = (const float*)d_in[0];
  const float* ty = (const float*)d_in[1];
  const float* xx = (const float*)d_in[2];
  const float* os = (const float*)d_in[3];
  const float* ls = (const float*)d_in[4];
  const float* ns = (const float*)d_in[5];
  float* out = (float*)d_out;
  (void)in_sizes; (void)n_in; (void)out_size;

  auto pad = [](size_t x) { return (x + 255) & ~(size_t)255; };
  size_t fixed = pad((size_t)N_TRAIN * KDIM * 2)
               + 3 * pad((size_t)N_TRAIN * 64) + pad((size_t)N_TRAIN * 4)
               + pad((size_t)N_TEST * 64) + pad((size_t)N_TEST * 4);
  int C = 4096;
  while (C > 256) {
    size_t tot = fixed + 3 * pad((size_t)C * KDIM * 2)
               + pad((size_t)C * 32) + pad((size_t)C * 4);
    if (tot <= ws_size) break;
    C >>= 1;
  }

  char* w = (char*)d_ws;
  auto alloc = [&](size_t bytes) { char* p = w; w += ((bytes + 255) & ~(size_t)255); return p; };
  unsigned short* Kb  = (unsigned short*)alloc((size_t)N_TRAIN * KDIM * 2);
  unsigned short* TPK = (unsigned short*)alloc((size_t)N_TRAIN * 64);
  unsigned short* THH = (unsigned short*)alloc((size_t)N_TRAIN * 64);
  unsigned short* TLL = (unsigned short*)alloc((size_t)N_TRAIN * 64);
  float* an = (float*)alloc((size_t)N_TRAIN * 4);
  unsigned short* XPK = (unsigned short*)alloc((size_t)N_TEST * 64);
  float* bn = (float*)alloc((size_t)N_TEST * 4);
  unsigned short* Rb = (unsigned short*)alloc((size_t)C * KDIM * 2);
  unsigned short* Pb = (unsigned short*)alloc((size_t)C * KDIM * 2);
  unsigned short* Qb = (unsigned short*)alloc((size_t)C * KDIM * 2);
  float* scal = (float*)alloc((size_t)C * 32);
  float* pq   = (float*)alloc((size_t)C * 4);

  prep_kernel<<<48, 256, 0, stream>>>(tx, xx, ls, TPK, THH, TLL, an, XPK, bn);

  build_mfma<true><<<dim3(KDIM / 128, N_TRAIN / 128), 256, 0, stream>>>(
      TPK, an, THH, TLL, an, Kb, os);

  for (int c0 = 0; c0 < N_TEST; c0 += C) {
    build_mfma<false><<<dim3(KDIM / 128, C / 128), 256, 0, stream>>>(
        XPK + (size_t)c0 * 32, bn + c0, THH, TLL, an, Rb, os);
    int gy = C / 256;
    dim3 gg(32 * gy);
    int scb = (C + 255) / 256;
    for (int it = 0; it < CG_ITERS; ++it) {
      const unsigned short* Ain = (it == 0) ? Rb : Pb;
      int fin = (it == CG_ITERS - 1) ? 1 : 0;
      if (!fin) {
        gemm256<0><<<gg, 512, 0, stream>>>(Ain, Kb, Qb, gy, pq);
        if (it == 0)
          cg_step<true><<<C, 256, 0, stream>>>(Qb, Rb, Pb, ty, scal, pq, os, ns);
        else
          cg_step<false><<<C, 256, 0, stream>>>(Qb, Rb, Pb, ty, scal, pq, os, ns);
      } else {
        gemm256<1><<<gg, 512, 0, stream>>>(Ain, Kb, Qb, gy, pq);
        final_out<<<scb, 256, 0, stream>>>(pq, scal, os, ns, out, c0, C);
      }
    }
  }
}

// Round 17
// 1920.350 us; speedup vs baseline: 2.0483x; 1.0049x over previous
//
#include <hip/hip_runtime.h>
#include <stdint.h>

// GP posterior via batched CG, 4 iterations. K_od bf16 (diag 0) + exact f32
// diagonal dg=s+sn in cg_step. Matvec = 256x256x64 8-phase counted-vmcnt MFMA
// GEMM (87% dense peak). Builds via split-bf16 MFMA. r17: cg_step micro-pack
// (analytic pp', LAST skips R store, scal loads hoisted above the reduce).

#define N_TRAIN 8192
#define N_TEST  4096
#define DIM     16
#define KDIM    8192
#define CG_ITERS 4
#define NT      (KDIM / 64)   // 128 K-tiles of BK=64

using f32x4  = __attribute__((ext_vector_type(4))) float;
using bf16x8 = __attribute__((ext_vector_type(8))) short;

static __device__ __forceinline__ unsigned short f2bf(float f) {
  unsigned u = __float_as_uint(f);
  u = (u + 0x7FFFu + ((u >> 16) & 1u)) >> 16;   // RNE
  return (unsigned short)u;
}
static __device__ __forceinline__ float bf2f(unsigned short h) {
  return __uint_as_float(((unsigned)h) << 16);
}

__device__ __forceinline__ void gl_lds16(const void* g, void* l) {
  __builtin_amdgcn_global_load_lds(
      (const __attribute__((address_space(1))) unsigned int*)g,
      (__attribute__((address_space(3))) unsigned int*)l, 16, 0, 0);
}

template <int N>
__device__ __forceinline__ void block_reduceN(float* v, float* sbuf) {
  #pragma unroll
  for (int off = 32; off > 0; off >>= 1)
    #pragma unroll
    for (int i = 0; i < N; ++i) v[i] += __shfl_down(v[i], off);
  int lane = threadIdx.x & 63, w = threadIdx.x >> 6;
  if (lane == 0)
    #pragma unroll
    for (int i = 0; i < N; ++i) sbuf[w * N + i] = v[i];
  __syncthreads();
  #pragma unroll
  for (int i = 0; i < N; ++i)
    v[i] = sbuf[i] + sbuf[N + i] + sbuf[2 * N + i] + sbuf[3 * N + i];
}

// ---- prep: split-bf16 packs + squared norms ----
__global__ void prep_kernel(const float* __restrict__ tx, const float* __restrict__ xx,
                            const float* __restrict__ ls,
                            unsigned short* __restrict__ TPK,
                            unsigned short* __restrict__ THH,
                            unsigned short* __restrict__ TLL,
                            float* __restrict__ an,
                            unsigned short* __restrict__ XPK,
                            float* __restrict__ bn) {
  int i = blockIdx.x * 256 + threadIdx.x;
  if (i < N_TRAIN) {
    float s = 0.f;
    #pragma unroll
    for (int d = 0; d < DIM; ++d) {
      float v = tx[(size_t)i * DIM + d] / ls[d];
      s += v * v;
      unsigned short hi = f2bf(v);
      unsigned short lo = f2bf(v - bf2f(hi));
      TPK[(size_t)i * 32 + d] = hi;  TPK[(size_t)i * 32 + 16 + d] = lo;
      THH[(size_t)i * 32 + d] = hi;  THH[(size_t)i * 32 + 16 + d] = hi;
      TLL[(size_t)i * 32 + d] = lo;  TLL[(size_t)i * 32 + 16 + d] = lo;
    }
    an[i] = s;
  } else if (i < N_TRAIN + N_TEST) {
    int j = i - N_TRAIN;
    float s = 0.f;
    #pragma unroll
    for (int d = 0; d < DIM; ++d) {
      float v = xx[(size_t)j * DIM + d] / ls[d];
      s += v * v;
      unsigned short hi = f2bf(v);
      unsigned short lo = f2bf(v - bf2f(hi));
      XPK[(size_t)j * 32 + d] = hi;  XPK[(size_t)j * 32 + 16 + d] = lo;
    }
    bn[j] = s;
  }
}

// ---- MFMA kernel-matrix builder (unchanged from r16) ----
#define TLDS 136

template <bool DIAG0>
__global__ __launch_bounds__(256) void build_mfma(
    const unsigned short* __restrict__ IPK,
    const float* __restrict__ nI,
    const unsigned short* __restrict__ JHH,
    const unsigned short* __restrict__ JLL,
    const float* __restrict__ nJ,
    unsigned short* __restrict__ O,
    const float* __restrict__ osc)
{
  __shared__ unsigned short tile[128 * TLDS];
  __shared__ float sI[128], sJ[128];
  int t = threadIdx.x, lane = t & 63, wave = t >> 6;
  int i0 = blockIdx.y * 128, j0 = blockIdx.x * 128;
  if (t < 128) sI[t] = nI[i0 + t];
  else         sJ[t - 128] = nJ[j0 + t - 128];
  __syncthreads();

  float s = osc[0];
  int ir = lane & 15, ks = lane >> 4;

  bf16x8 af[2];
  #pragma unroll
  for (int rt = 0; rt < 2; ++rt)
    af[rt] = *(const bf16x8*)&IPK[(size_t)(i0 + (wave * 2 + rt) * 16 + ir) * 32 + ks * 8];

  for (int jt = 0; jt < 8; ++jt) {
    bf16x8 bh = *(const bf16x8*)&JHH[(size_t)(j0 + jt * 16 + ir) * 32 + ks * 8];
    bf16x8 bl = *(const bf16x8*)&JLL[(size_t)(j0 + jt * 16 + ir) * 32 + ks * 8];
    f32x4 acc0 = {}, acc1 = {};
    acc0 = __builtin_amdgcn_mfma_f32_16x16x32_bf16(af[0], bh, acc0, 0, 0, 0);
    acc0 = __builtin_amdgcn_mfma_f32_16x16x32_bf16(af[0], bl, acc0, 0, 0, 0);
    acc1 = __builtin_amdgcn_mfma_f32_16x16x32_bf16(af[1], bh, acc1, 0, 0, 0);
    acc1 = __builtin_amdgcn_mfma_f32_16x16x32_bf16(af[1], bl, acc1, 0, 0, 0);
    #pragma unroll
    for (int rt = 0; rt < 2; ++rt) {
      f32x4 a = rt ? acc1 : acc0;
      #pragma unroll
      for (int rg = 0; rg < 4; ++rg) {
        int lrow = (wave * 2 + rt) * 16 + ks * 4 + rg;
        int lcol = jt * 16 + ir;
        float d2 = fmaxf(sI[lrow] + sJ[lcol] - 2.f * a[rg], 0.f);
        float v = s * __expf(-0.5f * d2);
        if (DIAG0 && (i0 + lrow == j0 + lcol)) v = 0.f;
        tile[lrow * TLDS + lcol] = f2bf(v);
      }
    }
  }
  __syncthreads();
  #pragma unroll
  for (int pass = 0; pass < 8; ++pass) {
    int r = pass * 16 + (t >> 4);
    int cb = (t & 15) * 8;
    *(bf16x8*)&O[(size_t)(i0 + r) * KDIM + j0 + cb] =
        *(const bf16x8*)&tile[r * TLDS + cb];
  }
}

// ============  256x256 8-phase pipelined MFMA GEMM (unchanged from r15)  ============
__device__ __forceinline__ void stage_h(const char* gtile, int kbyte,
                                        char* ldsdst, int tid, int wave) {
  #pragma unroll
  for (int q = 0; q < 2; ++q) {
    int o = q * 8192 + tid * 16;
    int r = o >> 7;
    int c = (o & 127) ^ ((r & 7) << 4);
    gl_lds16(gtile + (size_t)r * (KDIM * 2) + kbyte + c,
             ldsdst + q * 8192 + wave * 1024);
  }
}

template <int FINAL>
__global__ __launch_bounds__(512, 1) void gemm256(
    const unsigned short* __restrict__ A,
    const unsigned short* __restrict__ Bm,
    unsigned short* __restrict__ Cq,
    int gy, float* __restrict__ pq)
{
  __shared__ char Ab[2][2][16384];
  __shared__ char Bb[2][2][16384];
  const int tid = threadIdx.x, lane = tid & 63, wave = tid >> 6;
  const int wm = wave >> 2, wn = wave & 3;
  const int nwg = gridDim.x, orig = blockIdx.x;
  const int wgid = (orig & 7) * (nwg >> 3) + (orig >> 3);
  const int bx = wgid / gy, by = wgid % gy;
  const size_t HALF = (size_t)128 * KDIM * 2;

  const char* bA = (const char*)(A  + (size_t)(by * 256) * KDIM);
  const char* bB = (const char*)(Bm + (size_t)(bx * 256) * KDIM);

  const int ar = wm * 64 + (lane & 15);
  const int br = wn * 32 + (lane & 15);
  const int hi = (lane >> 4) * 16;
  int aoff[4][2], boff[2][2];
  #pragma unroll
  for (int mf = 0; mf < 4; ++mf)
    #pragma unroll
    for (int kk = 0; kk < 2; ++kk)
      aoff[mf][kk] = (ar + mf * 16) * 128 + ((hi + kk * 64) ^ ((ar & 7) << 4));
  #pragma unroll
  for (int nf = 0; nf < 2; ++nf)
    #pragma unroll
    for (int kk = 0; kk < 2; ++kk)
      boff[nf][kk] = (br + nf * 16) * 128 + ((hi + kk * 64) ^ ((br & 7) << 4));

  f32x4 acc[2][2][4][2] = {};
  bf16x8 aR[4][2], bR[2][2][2];

#define BAR() __builtin_amdgcn_s_barrier()
#define PRIO1 __builtin_amdgcn_s_setprio(1)
#define PRIO0 __builtin_amdgcn_s_setprio(0)
#define FENCE8() asm volatile("s_waitcnt vmcnt(8)" ::: "memory")
#define FENCE6() asm volatile("s_waitcnt vmcnt(6)" ::: "memory")
#define FENCE0() asm volatile("s_waitcnt vmcnt(0)" ::: "memory")
#define STAGE_A(buf, mh, kb) stage_h(bA + ((mh) ? HALF : 0), kb, &Ab[buf][mh][0], tid, wave)
#define STAGE_B(buf, mh, kb) stage_h(bB + ((mh) ? HALF : 0), kb, &Bb[buf][mh][0], tid, wave)
#define LOAD_A(buf, mh)                                                        \
  { _Pragma("unroll") for (int mf = 0; mf < 4; ++mf)                           \
      _Pragma("unroll") for (int kk = 0; kk < 2; ++kk)                         \
        aR[mf][kk] = *(const bf16x8*)(&Ab[buf][mh][0] + aoff[mf][kk]); }
#define LOAD_B(buf, nh)                                                        \
  { _Pragma("unroll") for (int nf = 0; nf < 2; ++nf)                           \
      _Pragma("unroll") for (int kk = 0; kk < 2; ++kk)                         \
        bR[nh][nf][kk] = *(const bf16x8*)(&Bb[buf][nh][0] + boff[nf][kk]); }
#define MFMA16(mh, nh)                                                         \
  { _Pragma("unroll") for (int kk = 0; kk < 2; ++kk)                           \
      _Pragma("unroll") for (int mf = 0; mf < 4; ++mf)                         \
        _Pragma("unroll") for (int nf = 0; nf < 2; ++nf)                       \
          acc[mh][nh][mf][nf] = __builtin_amdgcn_mfma_f32_16x16x32_bf16(       \
              aR[mf][kk], bR[nh][nf][kk], acc[mh][nh][mf][nf], 0, 0, 0); }

  STAGE_A(0, 0, 0);   STAGE_B(0, 0, 0);   STAGE_B(0, 1, 0);   STAGE_A(0, 1, 0);
  STAGE_A(1, 0, 128); STAGE_B(1, 0, 128); STAGE_B(1, 1, 128); STAGE_A(1, 1, 128);
  FENCE6();
  BAR();

  for (int t = 0; t < NT; t += 2) {
    const bool g = (t + 2 < NT);
    const int kb2 = (t + 2) * 128, kb3 = (t + 3) * 128;
    LOAD_A(0, 0); LOAD_B(0, 0);
    BAR(); PRIO1; MFMA16(0, 0); PRIO0; BAR();
    if (g) STAGE_A(0, 0, kb2);
    LOAD_B(0, 1);
    BAR(); PRIO1; MFMA16(0, 1); PRIO0; BAR();
    if (g) STAGE_B(0, 0, kb2);
    LOAD_A(0, 1);
    BAR(); PRIO1; MFMA16(1, 0); PRIO0; BAR();
    if (g) { STAGE_B(0, 1, kb2); STAGE_A(0, 1, kb2); }
    BAR(); PRIO1; MFMA16(1, 1); PRIO0;
    if (g) { FENCE8(); } else { FENCE0(); }
    BAR();
    LOAD_A(1, 0); LOAD_B(1, 0);
    BAR(); PRIO1; MFMA16(0, 0); PRIO0; BAR();
    if (g) STAGE_A(1, 0, kb3);
    LOAD_B(1, 1);
    BAR(); PRIO1; MFMA16(0, 1); PRIO0; BAR();
    if (g) STAGE_B(1, 0, kb3);
    LOAD_A(1, 1);
    BAR(); PRIO1; MFMA16(1, 0); PRIO0; BAR();
    if (g) { STAGE_B(1, 1, kb3); STAGE_A(1, 1, kb3); }
    BAR(); PRIO1; MFMA16(1, 1); PRIO0;
    if (g) { FENCE6(); }
    BAR();
  }

  const int bm = by * 256, bn = bx * 256;
  if (!FINAL) {
    #pragma unroll
    for (int mh = 0; mh < 2; ++mh)
      #pragma unroll
      for (int nh = 0; nh < 2; ++nh)
        #pragma unroll
        for (int mf = 0; mf < 4; ++mf)
          #pragma unroll
          for (int nf = 0; nf < 2; ++nf) {
            int row = bm + mh * 128 + wm * 64 + mf * 16 + (lane >> 4) * 4;
            int col = bn + nh * 128 + wn * 32 + nf * 16 + (lane & 15);
            #pragma unroll
            for (int rg = 0; rg < 4; ++rg)
              Cq[(size_t)(row + rg) * KDIM + col] = f2bf(acc[mh][nh][mf][nf][rg]);
          }
  } else {
    #pragma unroll
    for (int mh = 0; mh < 2; ++mh)
      #pragma unroll
      for (int mf = 0; mf < 4; ++mf)
        #pragma unroll
        for (int rg = 0; rg < 4; ++rg) {
          int row = bm + mh * 128 + wm * 64 + mf * 16 + (lane >> 4) * 4 + rg;
          float v = 0.f;
          #pragma unroll
          for (int nh = 0; nh < 2; ++nh)
            #pragma unroll
            for (int nf = 0; nf < 2; ++nf) {
              int col = bn + nh * 128 + wn * 32 + nf * 16 + (lane & 15);
              v += acc[mh][nh][mf][nf][rg] * bf2f(A[(size_t)row * KDIM + col]);
            }
          v += __shfl_xor(v, 1); v += __shfl_xor(v, 2);
          v += __shfl_xor(v, 4); v += __shfl_xor(v, 8);
          if ((lane & 15) == 0) atomicAdd(&pq[row], v);
        }
  }
#undef MFMA16
#undef LOAD_B
#undef LOAD_A
#undef STAGE_B
#undef STAGE_A
#undef FENCE0
#undef FENCE6
#undef FENCE8
#undef PRIO0
#undef PRIO1
#undef BAR
}

// ---- CG step: exact-diagonal recurrence; ONE reduce; analytic pp';
// LAST skips the R store (R dead after final cg_step). ----
template <bool FIRST, bool LAST>
__global__ __launch_bounds__(256) void cg_step(
    const unsigned short* __restrict__ Q, unsigned short* __restrict__ R,
    unsigned short* __restrict__ P, const float* __restrict__ y,
    float* __restrict__ scal, float* __restrict__ pq,
    const float* __restrict__ osc, const float* __restrict__ noi)
{
  __shared__ float sbuf[24];
  int c = blockIdx.x, t = threadIdx.x;
  size_t base = (size_t)c * KDIM;
  float dg = osc[0] + noi[0];

  // hoist state loads (independent of the reduce; hide their latency)
  float rr_s = 0.f, yp_s = 0.f, yr_s = 0.f, mean_s = 0.f, bx_s = 0.f;
  if (!FIRST) {
    rr_s = scal[c*8+0]; yp_s = scal[c*8+1]; yr_s = scal[c*8+2];
    mean_s = scal[c*8+3]; bx_s = scal[c*8+4];
  }

  bf16x8 q8[4], r8[4], p8[4];
  #pragma unroll
  for (int k = 0; k < 4; ++k) q8[k] = *(const bf16x8*)&Q[base + k * 2048 + t * 8];
  #pragma unroll
  for (int k = 0; k < 4; ++k) r8[k] = *(const bf16x8*)&R[base + k * 2048 + t * 8];
  if (FIRST) {
    #pragma unroll
    for (int k = 0; k < 4; ++k) p8[k] = r8[k];
  } else {
    #pragma unroll
    for (int k = 0; k < 4; ++k) p8[k] = *(const bf16x8*)&P[base + k * 2048 + t * 8];
  }

  // FIRST: v = {r.q, q.q, y.q, r.r, y.r, -}; MID/LAST: v = {p.q, r.q, q.q, y.q, p.p, r.p}
  float v[6] = {0.f, 0.f, 0.f, 0.f, 0.f, 0.f};
  #pragma unroll
  for (int k = 0; k < 4; ++k) {
    int j = k * 2048 + t * 8;
    f32x4 ya = *(const f32x4*)&y[j];
    f32x4 yb = *(const f32x4*)&y[j + 4];
    #pragma unroll
    for (int e = 0; e < 8; ++e) {
      float qv = bf2f((unsigned short)q8[k][e]);
      float rv = bf2f((unsigned short)r8[k][e]);
      float yv = (e < 4) ? ya[e] : yb[e - 4];
      if (FIRST) {
        v[0] += rv * qv; v[1] += qv * qv; v[2] += yv * qv;
        v[3] += rv * rv; v[4] += yv * rv;
      } else {
        float pv = bf2f((unsigned short)p8[k][e]);
        v[0] += pv * qv; v[1] += rv * qv; v[2] += qv * qv; v[3] += yv * qv;
        v[4] += pv * pv; v[5] += rv * pv;
      }
    }
  }
  block_reduceN<6>(v, sbuf);

  float rr, yp, yr, mean, bx;
  float pq_od, rq_od, qq_od, yq_od, pp, rp;
  if (FIRST) {
    rr = v[3]; yp = v[4]; yr = v[4]; mean = 0.f; bx = 0.f;
    pq_od = v[0]; rq_od = v[0]; qq_od = v[1]; yq_od = v[2];
    pp = v[3]; rp = v[3];
  } else {
    rr = rr_s; yp = yp_s; yr = yr_s; mean = mean_s; bx = bx_s;
    pq_od = v[0]; rq_od = v[1]; qq_od = v[2]; yq_od = v[3];
    pp = v[4]; rp = v[5];
  }
  float pAp   = pq_od + dg * pp;
  float rq_e  = rq_od + dg * rp;
  float qq_e  = qq_od + 2.f * dg * pq_od + dg * dg * pp;
  float yq_e  = yq_od + dg * yp;

  float alpha = rr / fmaxf(pAp, 1e-30f);
  mean += alpha * yp;
  bx   += alpha * rr;
  float rrn = fmaxf(rr - 2.f * alpha * rq_e + alpha * alpha * qq_e, 0.f);
  float yrn = yr - alpha * yq_e;
  float beta = rrn / fmaxf(rr, 1e-30f);
  float ypn  = yrn + beta * yp;
  // analytic pp' = r'.r' + 2b r'.p + b^2 p.p ; r'.p = r.p - alpha*pAp
  float rpn = rp - alpha * pAp;
  float ppn = fmaxf(rrn + 2.f * beta * rpn + beta * beta * pp, 0.f);

  // fused update: r' = r - alpha*(q + dg*p) [store unless LAST]; p' = r' + beta*p
  #pragma unroll
  for (int k = 0; k < 4; ++k) {
    int j = k * 2048 + t * 8;
    bf16x8 wr, wp;
    #pragma unroll
    for (int e = 0; e < 8; ++e) {
      float pv = bf2f((unsigned short)p8[k][e]);
      float qe = bf2f((unsigned short)q8[k][e]) + dg * pv;
      float rn = bf2f((unsigned short)r8[k][e]) - alpha * qe;
      unsigned short hb = f2bf(rn);
      wr[e] = (short)hb;
      wp[e] = (short)f2bf(bf2f(hb) + beta * pv);
    }
    if (!LAST) *(bf16x8*)&R[base + j] = wr;
    *(bf16x8*)&P[base + j] = wp;
  }
  if (t == 0) {
    scal[c*8+0] = rrn; scal[c*8+1] = ypn; scal[c*8+2] = yrn;
    scal[c*8+3] = mean; scal[c*8+4] = bx; scal[c*8+5] = ppn;
    pq[c] = 0.f;
  }
}

// ---- final outputs ----
__global__ void final_out(float* __restrict__ pq, const float* __restrict__ scal,
                          const float* __restrict__ osc, const float* __restrict__ noi,
                          float* __restrict__ out, int c0, int C)
{
  int c = blockIdx.x * 256 + threadIdx.x;
  if (c >= C) return;
  float dg = osc[0] + noi[0];
  float rr = scal[c*8+0], yp = scal[c*8+1];
  float mean = scal[c*8+3], bx = scal[c*8+4], pp = scal[c*8+5];
  float pAp = pq[c] + dg * pp;
  float alpha = rr / fmaxf(pAp, 1e-30f);
  mean += alpha * yp;
  bx   += alpha * rr;
  out[c0 + c] = mean;
  out[N_TEST + c0 + c] = dg - bx;
  pq[c] = 0.f;
}

extern "C" void kernel_launch(void* const* d_in, const int* in_sizes, int n_in,
                              void* d_out, int out_size, void* d_ws, size_t ws_size,
                              hipStream_t stream) {
  const float* tx = (const float*)d_in[0];
  const float* ty = (const float*)d_in[1];
  const float* xx = (const float*)d_in[2];
  const float* os = (const float*)d_in[3];
  const float* ls = (const float*)d_in[4];
  const float* ns = (const float*)d_in[5];
  float* out = (float*)d_out;
  (void)in_sizes; (void)n_in; (void)out_size;

  auto pad = [](size_t x) { return (x + 255) & ~(size_t)255; };
  size_t fixed = pad((size_t)N_TRAIN * KDIM * 2)
               + 3 * pad((size_t)N_TRAIN * 64) + pad((size_t)N_TRAIN * 4)
               + pad((size_t)N_TEST * 64) + pad((size_t)N_TEST * 4);
  int C = 4096;
  while (C > 256) {
    size_t tot = fixed + 3 * pad((size_t)C * KDIM * 2)
               + pad((size_t)C * 32) + pad((size_t)C * 4);
    if (tot <= ws_size) break;
    C >>= 1;
  }

  char* w = (char*)d_ws;
  auto alloc = [&](size_t bytes) { char* p = w; w += ((bytes + 255) & ~(size_t)255); return p; };
  unsigned short* Kb  = (unsigned short*)alloc((size_t)N_TRAIN * KDIM * 2);
  unsigned short* TPK = (unsigned short*)alloc((size_t)N_TRAIN * 64);
  unsigned short* THH = (unsigned short*)alloc((size_t)N_TRAIN * 64);
  unsigned short* TLL = (unsigned short*)alloc((size_t)N_TRAIN * 64);
  float* an = (float*)alloc((size_t)N_TRAIN * 4);
  unsigned short* XPK = (unsigned short*)alloc((size_t)N_TEST * 64);
  float* bn = (float*)alloc((size_t)N_TEST * 4);
  unsigned short* Rb = (unsigned short*)alloc((size_t)C * KDIM * 2);
  unsigned short* Pb = (unsigned short*)alloc((size_t)C * KDIM * 2);
  unsigned short* Qb = (unsigned short*)alloc((size_t)C * KDIM * 2);
  float* scal = (float*)alloc((size_t)C * 32);
  float* pq   = (float*)alloc((size_t)C * 4);

  prep_kernel<<<48, 256, 0, stream>>>(tx, xx, ls, TPK, THH, TLL, an, XPK, bn);

  build_mfma<true><<<dim3(KDIM / 128, N_TRAIN / 128), 256, 0, stream>>>(
      TPK, an, THH, TLL, an, Kb, os);

  for (int c0 = 0; c0 < N_TEST; c0 += C) {
    build_mfma<false><<<dim3(KDIM / 128, C / 128), 256, 0, stream>>>(
        XPK + (size_t)c0 * 32, bn + c0, THH, TLL, an, Rb, os);
    int gy = C / 256;
    dim3 gg(32 * gy);
    int scb = (C + 255) / 256;
    for (int it = 0; it < CG_ITERS; ++it) {
      const unsigned short* Ain = (it == 0) ? Rb : Pb;
      int fin = (it == CG_ITERS - 1) ? 1 : 0;
      if (!fin) {
        gemm256<0><<<gg, 512, 0, stream>>>(Ain, Kb, Qb, gy, pq);
        if (it == 0)
          cg_step<true, false><<<C, 256, 0, stream>>>(Qb, Rb, Pb, ty, scal, pq, os, ns);
        else if (it < CG_ITERS - 2)
          cg_step<false, false><<<C, 256, 0, stream>>>(Qb, Rb, Pb, ty, scal, pq, os, ns);
        else
          cg_step<false, true><<<C, 256, 0, stream>>>(Qb, Rb, Pb, ty, scal, pq, os, ns);
      } else {
        gemm256<1><<<gg, 512, 0, stream>>>(Ain, Kb, Qb, gy, pq);
        final_out<<<scb, 256, 0, stream>>>(pq, scal, os, ns, out, c0, C);
      }
    }
  }
}